// Round 1
// baseline (4688.263 us; speedup 1.0000x reference)
//
#include <hip/hip_runtime.h>

#define NNODES 100000
#define NEDGES 600000
#define DIM    128
#define NB     64
#define DFC    512

// ---------------------------------------------------------------------------
// Transpose a [128,128] weight (row-major [out,in]) into WT [in][out] so the
// GEMM can read W^T rows coalesced (float4 across out-cols).
__global__ __launch_bounds__(256) void transpose_w(const float* __restrict__ W,
                                                   float* __restrict__ WT) {
    int i = blockIdx.x * 256 + threadIdx.x;      // 0..16383
    int c = i >> 7;                              // out index
    int k = i & 127;                             // in index
    WT[k * 128 + c] = W[c * 128 + k];
}

// ---------------------------------------------------------------------------
// Fused q/k/v/skip GEMM: for 32 rows of x, compute x@W^T + b for 4 matrices.
// skip result written to BOTH o1 and h2 (the two per-graph accumulators).
// Safe when x == h2: each block reads only its own rows (into LDS) before
// writing them.
__global__ __launch_bounds__(256) void qkvs_kernel(
    const float* __restrict__ x,
    const float* __restrict__ wtq, const float* __restrict__ bq,
    const float* __restrict__ wtk, const float* __restrict__ bk,
    const float* __restrict__ wtv, const float* __restrict__ bv,
    const float* __restrict__ wts, const float* __restrict__ bs,
    float* __restrict__ q, float* __restrict__ k, float* __restrict__ v,
    float* __restrict__ o1, float* __restrict__ h2)
{
    __shared__ float xs[32][128];
    const int tid  = threadIdx.x;
    const int row0 = blockIdx.x * 32;

    const float4* xg4 = (const float4*)(x + (size_t)row0 * DIM);
    float4* xs4 = (float4*)&xs[0][0];
    for (int i = tid; i < 32 * 32; i += 256) xs4[i] = xg4[i];
    __syncthreads();

    const int cgi = tid & 31;         // float4-column index (cols 4*cgi..+3)
    const int rg  = (tid >> 5) * 4;   // rows rg..rg+3 within tile

    const float* WT[4]  = {wtq, wtk, wtv, wts};
    const float* BV[4]  = {bq, bk, bv, bs};
    float*       OUT[4] = {q, k, v, o1};

    for (int m = 0; m < 4; ++m) {
        const float4* wt4 = (const float4*)WT[m];
        float acc[4][4] = {};
        for (int kk = 0; kk < 128; kk += 4) {
            float4 w0 = wt4[(kk + 0) * 32 + cgi];
            float4 w1 = wt4[(kk + 1) * 32 + cgi];
            float4 w2 = wt4[(kk + 2) * 32 + cgi];
            float4 w3 = wt4[(kk + 3) * 32 + cgi];
#pragma unroll
            for (int i = 0; i < 4; ++i) {
                float4 xv = *(const float4*)&xs[rg + i][kk];
                acc[i][0] = fmaf(xv.x, w0.x, fmaf(xv.y, w1.x, fmaf(xv.z, w2.x, fmaf(xv.w, w3.x, acc[i][0]))));
                acc[i][1] = fmaf(xv.x, w0.y, fmaf(xv.y, w1.y, fmaf(xv.z, w2.y, fmaf(xv.w, w3.y, acc[i][1]))));
                acc[i][2] = fmaf(xv.x, w0.z, fmaf(xv.y, w1.z, fmaf(xv.z, w2.z, fmaf(xv.w, w3.z, acc[i][2]))));
                acc[i][3] = fmaf(xv.x, w0.w, fmaf(xv.y, w1.w, fmaf(xv.z, w2.w, fmaf(xv.w, w3.w, acc[i][3]))));
            }
        }
        const float4 bias = *(const float4*)&BV[m][cgi * 4];
        float* Op = OUT[m];
#pragma unroll
        for (int i = 0; i < 4; ++i) {
            float4 r;
            r.x = acc[i][0] + bias.x;
            r.y = acc[i][1] + bias.y;
            r.z = acc[i][2] + bias.z;
            r.w = acc[i][3] + bias.w;
            size_t off = (size_t)(row0 + rg + i) * DIM + cgi * 4;
            *(float4*)&Op[off] = r;
            if (m == 3) *(float4*)&h2[off] = r;
        }
    }
}

// ---------------------------------------------------------------------------
// Monotone uint encoding of float for atomicMax-based segment max.
__device__ __forceinline__ unsigned int fenc(float f) {
    unsigned int u = __float_as_uint(f);
    return (u & 0x80000000u) ? ~u : (u | 0x80000000u);
}
__device__ __forceinline__ float fdec(unsigned int key) {
    unsigned int u = (key & 0x80000000u) ? (key ^ 0x80000000u) : ~key;
    return __uint_as_float(u);
}

// One wave per edge: logits[e] = scale * dot(q[dst], k[src] + edge_attr@we.T)
// and atomic segment-max into mkey[dst].
__global__ __launch_bounds__(256) void edge_logits_kernel(
    const int* __restrict__ ei, const float* __restrict__ ea,
    const float* __restrict__ we,
    const float* __restrict__ q, const float* __restrict__ k,
    float* __restrict__ wbuf, unsigned int* __restrict__ mkey)
{
    const int wave = threadIdx.x >> 6;
    const int lane = threadIdx.x & 63;
    const int e = blockIdx.x * 4 + wave;
    if (e >= NEDGES) return;
    const int src = ei[e];
    const int dst = ei[NEDGES + e];
    const float a0 = ea[e * 3 + 0], a1 = ea[e * 3 + 1], a2 = ea[e * 3 + 2];
    const int c0 = lane, c1 = lane + 64;
    float e0 = fmaf(a0, we[c0 * 3 + 0], fmaf(a1, we[c0 * 3 + 1], a2 * we[c0 * 3 + 2]));
    float e1 = fmaf(a0, we[c1 * 3 + 0], fmaf(a1, we[c1 * 3 + 1], a2 * we[c1 * 3 + 2]));
    float val = q[(size_t)dst * DIM + c0] * (k[(size_t)src * DIM + c0] + e0)
              + q[(size_t)dst * DIM + c1] * (k[(size_t)src * DIM + c1] + e1);
#pragma unroll
    for (int off = 32; off > 0; off >>= 1) val += __shfl_xor(val, off, 64);
    if (lane == 0) {
        float logit = val * 0.08838834764831845f;   // 1/sqrt(128)
        wbuf[e] = logit;
        atomicMax(&mkey[dst], fenc(logit));
    }
}

// w = exp(logit - m[dst]); den[dst] += w (atomic); wbuf overwritten with w.
__global__ __launch_bounds__(256) void edge_softmax_kernel(
    const int* __restrict__ ei, const unsigned int* __restrict__ mkey,
    float* __restrict__ wbuf, float* __restrict__ den)
{
    const int e = blockIdx.x * 256 + threadIdx.x;
    if (e >= NEDGES) return;
    const int dst = ei[NEDGES + e];
    const float m = fdec(mkey[dst]);
    const float w = expf(wbuf[e] - m);
    wbuf[e] = w;
    atomicAdd(&den[dst], w);
}

// out[dst] += alpha * (v[src] + e);  2 edges per block, 128 threads per edge.
__global__ __launch_bounds__(256) void edge_scatter_kernel(
    const int* __restrict__ ei, const float* __restrict__ ea,
    const float* __restrict__ we, const float* __restrict__ v,
    const float* __restrict__ wbuf, const float* __restrict__ den,
    float* __restrict__ out)
{
    const int e = blockIdx.x * 2 + (threadIdx.x >> 7);
    const int c = threadIdx.x & 127;
    if (e >= NEDGES) return;
    const int src = ei[e];
    const int dst = ei[NEDGES + e];
    const float alpha = wbuf[e] / (den[dst] + 1e-16f);
    const float a0 = ea[e * 3 + 0], a1 = ea[e * 3 + 1], a2 = ea[e * 3 + 2];
    const float ec = fmaf(a0, we[c * 3 + 0], fmaf(a1, we[c * 3 + 1], a2 * we[c * 3 + 2]));
    atomicAdd(&out[(size_t)dst * DIM + c], alpha * (v[(size_t)src * DIM + c] + ec));
}

// h = relu(h) - relu(o1)   (h holds graph-2 conv output, in place)
__global__ __launch_bounds__(256) void combine_kernel(
    const float4* __restrict__ o1, float4* __restrict__ h)
{
    const int i = blockIdx.x * 256 + threadIdx.x;
    float4 a = o1[i];
    float4 b = h[i];
    float4 r;
    r.x = fmaxf(b.x, 0.f) - fmaxf(a.x, 0.f);
    r.y = fmaxf(b.y, 0.f) - fmaxf(a.y, 0.f);
    r.z = fmaxf(b.z, 0.f) - fmaxf(a.z, 0.f);
    r.w = fmaxf(b.w, 0.f) - fmaxf(a.w, 0.f);
    h[i] = r;
}

// Mean-pool prep: batchs is sorted, so accumulate runs in registers and
// flush one atomic per (b-boundary, feature).
__global__ __launch_bounds__(256) void pool_kernel(
    const float* __restrict__ h, const int* __restrict__ batchs,
    float* __restrict__ sums, float* __restrict__ cnt)
{
    const int sub = threadIdx.x >> 7;     // 0..1
    const int c = threadIdx.x & 127;
    int n0 = blockIdx.x * 32 + sub * 16;
    int nend = n0 + 16;
    if (nend > NNODES) nend = NNODES;
    float acc = 0.f, ccnt = 0.f;
    int curb = -1;
    for (int nd = n0; nd < nend; ++nd) {
        int b = batchs[nd];
        if (b != curb) {
            if (curb >= 0) {
                atomicAdd(&sums[curb * DIM + c], acc);
                if (c == 0) atomicAdd(&cnt[curb], ccnt);
            }
            acc = 0.f; ccnt = 0.f; curb = b;
        }
        acc += h[(size_t)nd * DIM + c];
        ccnt += 1.f;
    }
    if (curb >= 0) {
        atomicAdd(&sums[curb * DIM + c], acc);
        if (c == 0) atomicAdd(&cnt[curb], ccnt);
    }
}

// Whole MLP head per batch row: mean, fc0+relu, fc1+relu, fc3, log_softmax.
__global__ __launch_bounds__(256) void head_kernel(
    const float* __restrict__ sums, const float* __restrict__ cnt,
    const float* __restrict__ l0w, const float* __restrict__ l0b,
    const float* __restrict__ l1w, const float* __restrict__ l1b,
    const float* __restrict__ l3w, const float* __restrict__ l3b,
    float* __restrict__ out)
{
    __shared__ float g[DIM];
    __shared__ float h0[DFC];
    __shared__ float h1[DFC];
    __shared__ float lg[2];
    const int b = blockIdx.x;
    const int tid = threadIdx.x;
    const float c = fmaxf(cnt[b], 1.0f);
    if (tid < DIM) g[tid] = sums[b * DIM + tid] / c;
    __syncthreads();
    for (int o = tid; o < DFC; o += 256) {
        float acc = l0b[o];
        for (int kk = 0; kk < DIM; ++kk) acc = fmaf(g[kk], l0w[o * DIM + kk], acc);
        h0[o] = fmaxf(acc, 0.f);
    }
    __syncthreads();
    for (int o = tid; o < DFC; o += 256) {
        float acc = l1b[o];
        for (int kk = 0; kk < DFC; ++kk) acc = fmaf(h0[kk], l1w[o * DFC + kk], acc);
        h1[o] = fmaxf(acc, 0.f);
    }
    __syncthreads();
    if (tid < 2) {
        float acc = l3b[tid];
        for (int kk = 0; kk < DFC; ++kk) acc = fmaf(h1[kk], l3w[tid * DFC + kk], acc);
        lg[tid] = acc;
    }
    __syncthreads();
    if (tid == 0) {
        float l0 = lg[0], l1v = lg[1];
        float mx = fmaxf(l0, l1v);
        float lse = mx + logf(expf(l0 - mx) + expf(l1v - mx));
        out[b * 2 + 0] = l0 - lse;
        out[b * 2 + 1] = l1v - lse;
    }
}

// ---------------------------------------------------------------------------
extern "C" void kernel_launch(void* const* d_in, const int* in_sizes, int n_in,
                              void* d_out, int out_size, void* d_ws, size_t ws_size,
                              hipStream_t stream)
{
    const float* x      = (const float*)d_in[0];
    const int*   ei1    = (const int*)d_in[1];
    const int*   ei2    = (const int*)d_in[2];
    const float* ea1    = (const float*)d_in[3];
    const float* ea2    = (const float*)d_in[4];
    const int*   batchs = (const int*)d_in[6];

    // workspace layout (floats): q,k,v,o1,h (N*D each), wbuf(E), mkey(N),
    // den(N), sums(B*D), cnt(B), wt(16*128*128)  -> ~260 MB total
    float* ws_f = (float*)d_ws;
    const size_t ND = (size_t)NNODES * DIM;
    float*        q    = ws_f;
    float*        kbuf = q + ND;
    float*        v    = kbuf + ND;
    float*        o1   = v + ND;
    float*        h    = o1 + ND;          // doubles as o2 and next-layer input
    float*        wbuf = h + ND;
    unsigned int* mkey = (unsigned int*)(wbuf + NEDGES);
    float*        den  = (float*)(mkey + NNODES);
    float*        sums = den + NNODES;
    float*        cnt  = sums + NB * DIM;
    float*        wt   = cnt + NB;          // 16 matrices of 16384 floats

    // Pre-transpose all 16 layer weight matrices.
    for (int li = 0; li < 4; ++li) {
        const float* wsrc[4];
        if (li == 0) {
            wsrc[0] = (const float*)d_in[7];
            wsrc[1] = (const float*)d_in[9];
            wsrc[2] = (const float*)d_in[11];
            wsrc[3] = (const float*)d_in[14];
        } else {
            int i = li - 1;
            wsrc[0] = (const float*)d_in[16] + (size_t)i * 16384;
            wsrc[1] = (const float*)d_in[18] + (size_t)i * 16384;
            wsrc[2] = (const float*)d_in[20] + (size_t)i * 16384;
            wsrc[3] = (const float*)d_in[23] + (size_t)i * 16384;
        }
        for (int m = 0; m < 4; ++m)
            transpose_w<<<64, 256, 0, stream>>>(wsrc[m], wt + ((size_t)li * 4 + m) * 16384);
    }

    const float* xin = x;
    for (int li = 0; li < 4; ++li) {
        const float *bq_, *bk_, *bv_, *bs_, *we_;
        if (li == 0) {
            bq_ = (const float*)d_in[8];
            bk_ = (const float*)d_in[10];
            bv_ = (const float*)d_in[12];
            bs_ = (const float*)d_in[15];
            we_ = (const float*)d_in[13];
        } else {
            int i = li - 1;
            bq_ = (const float*)d_in[17] + (size_t)i * DIM;
            bk_ = (const float*)d_in[19] + (size_t)i * DIM;
            bv_ = (const float*)d_in[21] + (size_t)i * DIM;
            bs_ = (const float*)d_in[24] + (size_t)i * DIM;
            we_ = (const float*)d_in[22] + (size_t)i * DIM * 3;
        }
        const float* wtq = wt + ((size_t)li * 4 + 0) * 16384;
        const float* wtk = wt + ((size_t)li * 4 + 1) * 16384;
        const float* wtv = wt + ((size_t)li * 4 + 2) * 16384;
        const float* wts = wt + ((size_t)li * 4 + 3) * 16384;

        qkvs_kernel<<<NNODES / 32, 256, 0, stream>>>(xin, wtq, bq_, wtk, bk_,
                                                     wtv, bv_, wts, bs_,
                                                     q, kbuf, v, o1, h);

        for (int gi = 0; gi < 2; ++gi) {
            const int*   ei   = gi ? ei2 : ei1;
            const float* ea   = gi ? ea2 : ea1;
            float*       outb = gi ? h : o1;
            hipMemsetAsync(mkey, 0, NNODES * sizeof(unsigned int), stream);
            hipMemsetAsync(den, 0, NNODES * sizeof(float), stream);
            edge_logits_kernel<<<NEDGES / 4, 256, 0, stream>>>(ei, ea, we_, q, kbuf, wbuf, mkey);
            edge_softmax_kernel<<<(NEDGES + 255) / 256, 256, 0, stream>>>(ei, mkey, wbuf, den);
            edge_scatter_kernel<<<NEDGES / 2, 256, 0, stream>>>(ei, ea, we_, v, wbuf, den, outb);
        }
        combine_kernel<<<(int)(ND / 1024), 256, 0, stream>>>((const float4*)o1, (float4*)h);
        xin = h;
    }

    hipMemsetAsync(sums, 0, NB * DIM * sizeof(float), stream);
    hipMemsetAsync(cnt, 0, NB * sizeof(float), stream);
    pool_kernel<<<(NNODES + 31) / 32, 256, 0, stream>>>(h, batchs, sums, cnt);
    head_kernel<<<NB, 256, 0, stream>>>(sums, cnt,
        (const float*)d_in[25], (const float*)d_in[26],
        (const float*)d_in[27], (const float*)d_in[28],
        (const float*)d_in[29], (const float*)d_in[30],
        (float*)d_out);
}

// Round 2
// 2479.742 us; speedup vs baseline: 1.8906x; 1.8906x over previous
//
#include <hip/hip_runtime.h>

#define NNODES 100000
#define NEDGES 600000
#define DIM    128
#define NB     64
#define DFC    512
#define NB1    391   // ceil(NNODES/256) blocks for the scan

// ---------------------------------------------------------------------------
__global__ __launch_bounds__(256) void transpose_w(const float* __restrict__ W,
                                                   float* __restrict__ WT) {
    int i = blockIdx.x * 256 + threadIdx.x;      // 0..16383
    int c = i >> 7;                              // out index
    int k = i & 127;                             // in index
    WT[k * 128 + c] = W[c * 128 + k];
}

// ---------------------------------------------------------------------------
// Fused q/k/v/skip GEMM: for 32 rows of x, compute x@W^T + b for 4 matrices.
// skip result written to BOTH o1 and h2. Safe when x == h2: each block reads
// only its own rows into LDS before writing them.
__global__ __launch_bounds__(256) void qkvs_kernel(
    const float* __restrict__ x,
    const float* __restrict__ wtq, const float* __restrict__ bq,
    const float* __restrict__ wtk, const float* __restrict__ bk,
    const float* __restrict__ wtv, const float* __restrict__ bv,
    const float* __restrict__ wts, const float* __restrict__ bs,
    float* __restrict__ q, float* __restrict__ k, float* __restrict__ v,
    float* __restrict__ o1, float* __restrict__ h2)
{
    __shared__ float xs[32][128];
    const int tid  = threadIdx.x;
    const int row0 = blockIdx.x * 32;

    const float4* xg4 = (const float4*)(x + (size_t)row0 * DIM);
    float4* xs4 = (float4*)&xs[0][0];
    for (int i = tid; i < 32 * 32; i += 256) xs4[i] = xg4[i];
    __syncthreads();

    const int cgi = tid & 31;         // float4-column index
    const int rg  = (tid >> 5) * 4;   // rows rg..rg+3 within tile

    const float* WT[4]  = {wtq, wtk, wtv, wts};
    const float* BV[4]  = {bq, bk, bv, bs};
    float*       OUT[4] = {q, k, v, o1};

    for (int m = 0; m < 4; ++m) {
        const float4* wt4 = (const float4*)WT[m];
        float acc[4][4] = {};
        for (int kk = 0; kk < 128; kk += 4) {
            float4 w0 = wt4[(kk + 0) * 32 + cgi];
            float4 w1 = wt4[(kk + 1) * 32 + cgi];
            float4 w2 = wt4[(kk + 2) * 32 + cgi];
            float4 w3 = wt4[(kk + 3) * 32 + cgi];
#pragma unroll
            for (int i = 0; i < 4; ++i) {
                float4 xv = *(const float4*)&xs[rg + i][kk];
                acc[i][0] = fmaf(xv.x, w0.x, fmaf(xv.y, w1.x, fmaf(xv.z, w2.x, fmaf(xv.w, w3.x, acc[i][0]))));
                acc[i][1] = fmaf(xv.x, w0.y, fmaf(xv.y, w1.y, fmaf(xv.z, w2.y, fmaf(xv.w, w3.y, acc[i][1]))));
                acc[i][2] = fmaf(xv.x, w0.z, fmaf(xv.y, w1.z, fmaf(xv.z, w2.z, fmaf(xv.w, w3.z, acc[i][2]))));
                acc[i][3] = fmaf(xv.x, w0.w, fmaf(xv.y, w1.w, fmaf(xv.z, w2.w, fmaf(xv.w, w3.w, acc[i][3]))));
            }
        }
        const float4 bias = *(const float4*)&BV[m][cgi * 4];
        float* Op = OUT[m];
#pragma unroll
        for (int i = 0; i < 4; ++i) {
            float4 r;
            r.x = acc[i][0] + bias.x;
            r.y = acc[i][1] + bias.y;
            r.z = acc[i][2] + bias.z;
            r.w = acc[i][3] + bias.w;
            size_t off = (size_t)(row0 + rg + i) * DIM + cgi * 4;
            *(float4*)&Op[off] = r;
            if (m == 3) *(float4*)&h2[off] = r;
        }
    }
}

// ---------------------------------------------------------------------------
// CSR build: histogram -> exclusive scan (3 kernels) -> stable-ish scatter.
__global__ __launch_bounds__(256) void hist_kernel(const int* __restrict__ ei,
                                                   int* __restrict__ deg) {
    int e = blockIdx.x * 256 + threadIdx.x;
    if (e < NEDGES) atomicAdd(&deg[ei[NEDGES + e]], 1);
}

__global__ __launch_bounds__(256) void scan1_kernel(const int* __restrict__ deg,
                                                    int* __restrict__ excl,
                                                    int* __restrict__ bsum) {
    __shared__ int s[256];
    const int tid = threadIdx.x;
    const int i = blockIdx.x * 256 + tid;
    const int v = (i < NNODES) ? deg[i] : 0;
    s[tid] = v;
    __syncthreads();
    for (int off = 1; off < 256; off <<= 1) {
        int t = (tid >= off) ? s[tid - off] : 0;
        __syncthreads();
        s[tid] += t;
        __syncthreads();
    }
    if (i < NNODES) excl[i] = s[tid] - v;
    if (tid == 255) bsum[blockIdx.x] = s[255];
}

__global__ __launch_bounds__(512) void scan2_kernel(int* __restrict__ bsum) {
    __shared__ int s[512];
    const int tid = threadIdx.x;
    const int v = (tid < NB1) ? bsum[tid] : 0;
    s[tid] = v;
    __syncthreads();
    for (int off = 1; off < 512; off <<= 1) {
        int t = (tid >= off) ? s[tid - off] : 0;
        __syncthreads();
        s[tid] += t;
        __syncthreads();
    }
    if (tid < NB1) bsum[tid] = s[tid] - v;   // exclusive
}

__global__ __launch_bounds__(256) void scan3_kernel(const int* __restrict__ excl,
                                                    const int* __restrict__ bsum,
                                                    int* __restrict__ rowptr) {
    const int i = blockIdx.x * 256 + threadIdx.x;
    if (i < NNODES) rowptr[i] = excl[i] + bsum[blockIdx.x];
    if (i == 0) rowptr[NNODES] = NEDGES;
}

__global__ __launch_bounds__(256) void scatter_edges_kernel(
    const int* __restrict__ ei, const int* __restrict__ rowptr,
    int* __restrict__ fill, int* __restrict__ ssrc, int* __restrict__ se) {
    int e = blockIdx.x * 256 + threadIdx.x;
    if (e >= NEDGES) return;
    int dst = ei[NEDGES + e];
    int pos = rowptr[dst] + atomicAdd(&fill[dst], 1);
    ssrc[pos] = ei[e];
    se[pos] = e;
}

// ---------------------------------------------------------------------------
// Fused edge phase: one wave per dst node, flash-style online softmax over
// its incoming edges. No atomics; out already holds the skip term.
__global__ __launch_bounds__(256) void attn_aggregate_kernel(
    const int* __restrict__ rowptr, const int* __restrict__ ssrc,
    const int* __restrict__ se, const float* __restrict__ ea,
    const float* __restrict__ we,
    const float* __restrict__ q, const float* __restrict__ k,
    const float* __restrict__ v, float* __restrict__ out)
{
    const int wave = threadIdx.x >> 6;
    const int lane = threadIdx.x & 63;
    const int d = blockIdx.x * 4 + wave;
    if (d >= NNODES) return;
    const int c0 = lane, c1 = lane + 64;
    const float w00 = we[c0 * 3 + 0], w01 = we[c0 * 3 + 1], w02 = we[c0 * 3 + 2];
    const float w10 = we[c1 * 3 + 0], w11 = we[c1 * 3 + 1], w12 = we[c1 * 3 + 2];
    const int p0 = rowptr[d], p1 = rowptr[d + 1];
    if (p0 == p1) return;
    const float scale = 0.08838834764831845f;   // 1/sqrt(128)
    const float q0 = q[(size_t)d * DIM + c0] * scale;
    const float q1 = q[(size_t)d * DIM + c1] * scale;
    float m = -INFINITY, den = 0.f, a0 = 0.f, a1 = 0.f;
    for (int p = p0; p < p1; ++p) {
        const int src = ssrc[p];
        const int e = se[p];
        const float ea0 = ea[e * 3 + 0], ea1 = ea[e * 3 + 1], ea2 = ea[e * 3 + 2];
        const float ep0 = fmaf(ea0, w00, fmaf(ea1, w01, ea2 * w02));
        const float ep1 = fmaf(ea0, w10, fmaf(ea1, w11, ea2 * w12));
        const float k0 = k[(size_t)src * DIM + c0] + ep0;
        const float k1 = k[(size_t)src * DIM + c1] + ep1;
        float l = fmaf(q0, k0, q1 * k1);
#pragma unroll
        for (int off = 32; off > 0; off >>= 1) l += __shfl_xor(l, off, 64);
        const float mn = fmaxf(m, l);
        const float sc = expf(m - mn);      // 0 on first edge (m = -inf)
        const float wE = expf(l - mn);
        den = den * sc + wE;
        const float v0 = v[(size_t)src * DIM + c0] + ep0;
        const float v1 = v[(size_t)src * DIM + c1] + ep1;
        a0 = fmaf(a0, sc, wE * v0);
        a1 = fmaf(a1, sc, wE * v1);
        m = mn;
    }
    const float inv = 1.f / (den + 1e-16f);
    out[(size_t)d * DIM + c0] += a0 * inv;
    out[(size_t)d * DIM + c1] += a1 * inv;
}

// h = relu(h) - relu(o1)   (in place)
__global__ __launch_bounds__(256) void combine_kernel(
    const float4* __restrict__ o1, float4* __restrict__ h)
{
    const int i = blockIdx.x * 256 + threadIdx.x;
    float4 a = o1[i];
    float4 b = h[i];
    float4 r;
    r.x = fmaxf(b.x, 0.f) - fmaxf(a.x, 0.f);
    r.y = fmaxf(b.y, 0.f) - fmaxf(a.y, 0.f);
    r.z = fmaxf(b.z, 0.f) - fmaxf(a.z, 0.f);
    r.w = fmaxf(b.w, 0.f) - fmaxf(a.w, 0.f);
    h[i] = r;
}

// Mean-pool prep: batchs sorted -> run accumulation, atomic flush per boundary.
__global__ __launch_bounds__(256) void pool_kernel(
    const float* __restrict__ h, const int* __restrict__ batchs,
    float* __restrict__ sums, float* __restrict__ cnt)
{
    const int sub = threadIdx.x >> 7;
    const int c = threadIdx.x & 127;
    int n0 = blockIdx.x * 32 + sub * 16;
    int nend = n0 + 16;
    if (nend > NNODES) nend = NNODES;
    float acc = 0.f, ccnt = 0.f;
    int curb = -1;
    for (int nd = n0; nd < nend; ++nd) {
        int b = batchs[nd];
        if (b != curb) {
            if (curb >= 0) {
                atomicAdd(&sums[curb * DIM + c], acc);
                if (c == 0) atomicAdd(&cnt[curb], ccnt);
            }
            acc = 0.f; ccnt = 0.f; curb = b;
        }
        acc += h[(size_t)nd * DIM + c];
        ccnt += 1.f;
    }
    if (curb >= 0) {
        atomicAdd(&sums[curb * DIM + c], acc);
        if (c == 0) atomicAdd(&cnt[curb], ccnt);
    }
}

// Whole MLP head per batch row.
__global__ __launch_bounds__(256) void head_kernel(
    const float* __restrict__ sums, const float* __restrict__ cnt,
    const float* __restrict__ l0w, const float* __restrict__ l0b,
    const float* __restrict__ l1w, const float* __restrict__ l1b,
    const float* __restrict__ l3w, const float* __restrict__ l3b,
    float* __restrict__ out)
{
    __shared__ float g[DIM];
    __shared__ float h0[DFC];
    __shared__ float h1[DFC];
    __shared__ float lg[2];
    const int b = blockIdx.x;
    const int tid = threadIdx.x;
    const float c = fmaxf(cnt[b], 1.0f);
    if (tid < DIM) g[tid] = sums[b * DIM + tid] / c;
    __syncthreads();
    for (int o = tid; o < DFC; o += 256) {
        float acc = l0b[o];
        for (int kk = 0; kk < DIM; ++kk) acc = fmaf(g[kk], l0w[o * DIM + kk], acc);
        h0[o] = fmaxf(acc, 0.f);
    }
    __syncthreads();
    for (int o = tid; o < DFC; o += 256) {
        float acc = l1b[o];
        for (int kk = 0; kk < DFC; ++kk) acc = fmaf(h0[kk], l1w[o * DFC + kk], acc);
        h1[o] = fmaxf(acc, 0.f);
    }
    __syncthreads();
    if (tid < 2) {
        float acc = l3b[tid];
        for (int kk = 0; kk < DFC; ++kk) acc = fmaf(h1[kk], l3w[tid * DFC + kk], acc);
        lg[tid] = acc;
    }
    __syncthreads();
    if (tid == 0) {
        float l0 = lg[0], l1v = lg[1];
        float mx = fmaxf(l0, l1v);
        float lse = mx + logf(expf(l0 - mx) + expf(l1v - mx));
        out[b * 2 + 0] = l0 - lse;
        out[b * 2 + 1] = l1v - lse;
    }
}

// ---------------------------------------------------------------------------
extern "C" void kernel_launch(void* const* d_in, const int* in_sizes, int n_in,
                              void* d_out, int out_size, void* d_ws, size_t ws_size,
                              hipStream_t stream)
{
    const float* x      = (const float*)d_in[0];
    const int*   ei1    = (const int*)d_in[1];
    const int*   ei2    = (const int*)d_in[2];
    const float* ea1    = (const float*)d_in[3];
    const float* ea2    = (const float*)d_in[4];
    const int*   batchs = (const int*)d_in[6];

    // workspace layout
    float* ws_f = (float*)d_ws;
    const size_t ND = (size_t)NNODES * DIM;
    float* q    = ws_f;
    float* kbuf = q + ND;
    float* v    = kbuf + ND;
    float* o1   = v + ND;
    float* h    = o1 + ND;                 // doubles as o2 and next-layer input
    float* sums = h + ND;
    float* cnt  = sums + NB * DIM;
    float* wt   = cnt + NB;                // 16 matrices of 16384 floats
    int*   ip   = (int*)(wt + 16 * 16384);
    int* rowptr1 = ip;                     // N+1
    int* rowptr2 = rowptr1 + (NNODES + 1);
    int* ssrc1   = rowptr2 + (NNODES + 1); // E
    int* se1     = ssrc1 + NEDGES;
    int* ssrc2   = se1 + NEDGES;
    int* se2     = ssrc2 + NEDGES;
    int* deg     = se2 + NEDGES;           // N temp
    int* excl    = deg + NNODES;           // N temp (reused as fill)
    int* bsum    = excl + NNODES;          // 512 temp

    // ---- Build CSR (dst-sorted) for both edge sets, once per launch ----
    for (int gi = 0; gi < 2; ++gi) {
        const int* ei = gi ? ei2 : ei1;
        int* rowptr = gi ? rowptr2 : rowptr1;
        int* ssrc   = gi ? ssrc2 : ssrc1;
        int* se     = gi ? se2 : se1;
        hipMemsetAsync(deg, 0, NNODES * sizeof(int), stream);
        hist_kernel<<<(NEDGES + 255) / 256, 256, 0, stream>>>(ei, deg);
        scan1_kernel<<<NB1, 256, 0, stream>>>(deg, excl, bsum);
        scan2_kernel<<<1, 512, 0, stream>>>(bsum);
        scan3_kernel<<<NB1, 256, 0, stream>>>(excl, bsum, rowptr);
        hipMemsetAsync(excl, 0, NNODES * sizeof(int), stream);   // reuse as fill
        scatter_edges_kernel<<<(NEDGES + 255) / 256, 256, 0, stream>>>(ei, rowptr, excl, ssrc, se);
    }

    // ---- Pre-transpose all 16 layer weight matrices ----
    for (int li = 0; li < 4; ++li) {
        const float* wsrc[4];
        if (li == 0) {
            wsrc[0] = (const float*)d_in[7];
            wsrc[1] = (const float*)d_in[9];
            wsrc[2] = (const float*)d_in[11];
            wsrc[3] = (const float*)d_in[14];
        } else {
            int i = li - 1;
            wsrc[0] = (const float*)d_in[16] + (size_t)i * 16384;
            wsrc[1] = (const float*)d_in[18] + (size_t)i * 16384;
            wsrc[2] = (const float*)d_in[20] + (size_t)i * 16384;
            wsrc[3] = (const float*)d_in[23] + (size_t)i * 16384;
        }
        for (int m = 0; m < 4; ++m)
            transpose_w<<<64, 256, 0, stream>>>(wsrc[m], wt + ((size_t)li * 4 + m) * 16384);
    }

    // ---- Layers ----
    const float* xin = x;
    for (int li = 0; li < 4; ++li) {
        const float *bq_, *bk_, *bv_, *bs_, *we_;
        if (li == 0) {
            bq_ = (const float*)d_in[8];
            bk_ = (const float*)d_in[10];
            bv_ = (const float*)d_in[12];
            bs_ = (const float*)d_in[15];
            we_ = (const float*)d_in[13];
        } else {
            int i = li - 1;
            bq_ = (const float*)d_in[17] + (size_t)i * DIM;
            bk_ = (const float*)d_in[19] + (size_t)i * DIM;
            bv_ = (const float*)d_in[21] + (size_t)i * DIM;
            bs_ = (const float*)d_in[24] + (size_t)i * DIM;
            we_ = (const float*)d_in[22] + (size_t)i * DIM * 3;
        }
        const float* wtq = wt + ((size_t)li * 4 + 0) * 16384;
        const float* wtk = wt + ((size_t)li * 4 + 1) * 16384;
        const float* wtv = wt + ((size_t)li * 4 + 2) * 16384;
        const float* wts = wt + ((size_t)li * 4 + 3) * 16384;

        qkvs_kernel<<<NNODES / 32, 256, 0, stream>>>(xin, wtq, bq_, wtk, bk_,
                                                     wtv, bv_, wts, bs_,
                                                     q, kbuf, v, o1, h);

        attn_aggregate_kernel<<<(NNODES + 3) / 4, 256, 0, stream>>>(
            rowptr1, ssrc1, se1, ea1, we_, q, kbuf, v, o1);
        attn_aggregate_kernel<<<(NNODES + 3) / 4, 256, 0, stream>>>(
            rowptr2, ssrc2, se2, ea2, we_, q, kbuf, v, h);

        combine_kernel<<<(int)(ND / 1024), 256, 0, stream>>>((const float4*)o1, (float4*)h);
        xin = h;
    }

    hipMemsetAsync(sums, 0, NB * DIM * sizeof(float), stream);
    hipMemsetAsync(cnt, 0, NB * sizeof(float), stream);
    pool_kernel<<<(NNODES + 31) / 32, 256, 0, stream>>>(h, batchs, sums, cnt);
    head_kernel<<<NB, 256, 0, stream>>>(sums, cnt,
        (const float*)d_in[25], (const float*)d_in[26],
        (const float*)d_in[27], (const float*)d_in[28],
        (const float*)d_in[29], (const float*)d_in[30],
        (float*)d_out);
}

// Round 4
// 2002.871 us; speedup vs baseline: 2.3408x; 1.2381x over previous
//
#include <hip/hip_runtime.h>

#define NNODES 100000
#define NEDGES 600000
#define DIM    128
#define NB     64
#define DFC    512
#define NB1    391   // ceil(NNODES/256) blocks for the scan

typedef __attribute__((ext_vector_type(8))) short short8v;
typedef __attribute__((ext_vector_type(4))) float float4v;

// ---------------------------------------------------------------------------
// Split all 16 layer weight matrices into bf16 hi/lo, stored MFMA-frag-major:
// idx = mat*16384 + ((ks*8 + nt)*64 + lane)*8 + j
// representing B[k][n] = W[n][k], k = ks*32 + (lane>>4)*8 + j, n = nt*16 + (lane&15)
__global__ __launch_bounds__(256) void wsplit_kernel(
    const float* __restrict__ c1q, const float* __restrict__ c1k,
    const float* __restrict__ c1v, const float* __restrict__ c1s,
    const float* __restrict__ csq, const float* __restrict__ csk,
    const float* __restrict__ csv, const float* __restrict__ css,
    short* __restrict__ whi, short* __restrict__ wlo)
{
    int t = blockIdx.x * 256 + threadIdx.x;     // 0..32767
    int mat = t >> 11;                          // 0..15
    int tt = t & 2047;
    int lane = tt & 63, nt = (tt >> 6) & 7, ks = tt >> 9;
    int li = mat >> 2, mm = mat & 3;
    const float* W;
    if (li == 0) W = (mm == 0) ? c1q : (mm == 1) ? c1k : (mm == 2) ? c1v : c1s;
    else {
        const float* base = (mm == 0) ? csq : (mm == 1) ? csk : (mm == 2) ? csv : css;
        W = base + (size_t)(li - 1) * 16384;
    }
    int n = nt * 16 + (lane & 15);
    int k0 = ks * 32 + (lane >> 4) * 8;
    size_t ob = (size_t)mat * 16384 + (size_t)((ks * 8 + nt) * 64 + lane) * 8;
#pragma unroll
    for (int j = 0; j < 8; ++j) {
        float w = W[n * 128 + k0 + j];
        unsigned ub = __float_as_uint(w);
        float lo = w - __uint_as_float(ub & 0xFFFF0000u);
        whi[ob + j] = (short)(ub >> 16);
        wlo[ob + j] = (short)(__float_as_uint(lo) >> 16);
    }
}

// ---------------------------------------------------------------------------
// Split-bf16 MFMA fused q/k/v/skip GEMM. Block = 32 rows, wave m (0..3) owns
// matrix m (q,k,v,skip) and computes 32x128 via 2x8 16x16x32 fragments,
// 3 MFMA products per fragment (hi*hi + hi*lo + lo*hi), f32 accumulate.
// x split to bf16 hi/lo on the fly (truncation split, exact remainder).
// Safe when x == h2: __syncthreads() before epilogue (all readers in block).
__global__ __launch_bounds__(256) void qkvs_mfma_kernel(
    const float* __restrict__ x,
    const short* __restrict__ whi, const short* __restrict__ wlo,
    const float* __restrict__ bq, const float* __restrict__ bk,
    const float* __restrict__ bv, const float* __restrict__ bs,
    float* __restrict__ q, float* __restrict__ k, float* __restrict__ v,
    float* __restrict__ o1, float* __restrict__ h2)
{
    const int lane = threadIdx.x & 63;
    const int m = threadIdx.x >> 6;
    const int r0 = blockIdx.x * 32;
    const int lrow = lane & 15;
    const int lgrp = lane >> 4;

    float4v acc[2][8] = {};
    const short* Whi = whi + (size_t)m * 16384;
    const short* Wlo = wlo + (size_t)m * 16384;

    for (int ks = 0; ks < 4; ++ks) {
        short8v ahi[2], alo[2];
#pragma unroll
        for (int mt = 0; mt < 2; ++mt) {
            const float* xp = x + (size_t)(r0 + mt * 16 + lrow) * DIM + ks * 32 + lgrp * 8;
            float4 xa = *(const float4*)xp;
            float4 xb = *(const float4*)(xp + 4);
            float xs[8] = {xa.x, xa.y, xa.z, xa.w, xb.x, xb.y, xb.z, xb.w};
#pragma unroll
            for (int j = 0; j < 8; ++j) {
                unsigned ub = __float_as_uint(xs[j]);
                float lo = xs[j] - __uint_as_float(ub & 0xFFFF0000u);
                ahi[mt][j] = (short)(ub >> 16);
                alo[mt][j] = (short)(__float_as_uint(lo) >> 16);
            }
        }
        const short* bh = Whi + (size_t)((ks * 8) * 64 + lane) * 8;
        const short* bl = Wlo + (size_t)((ks * 8) * 64 + lane) * 8;
#pragma unroll
        for (int nt = 0; nt < 8; ++nt) {
            short8v bhi = *(const short8v*)(bh + (size_t)nt * 512);
            short8v blo = *(const short8v*)(bl + (size_t)nt * 512);
#pragma unroll
            for (int mt = 0; mt < 2; ++mt) {
                acc[mt][nt] = __builtin_amdgcn_mfma_f32_16x16x32_bf16(ahi[mt], bhi, acc[mt][nt], 0, 0, 0);
                acc[mt][nt] = __builtin_amdgcn_mfma_f32_16x16x32_bf16(ahi[mt], blo, acc[mt][nt], 0, 0, 0);
                acc[mt][nt] = __builtin_amdgcn_mfma_f32_16x16x32_bf16(alo[mt], bhi, acc[mt][nt], 0, 0, 0);
            }
        }
    }

    __syncthreads();   // all x reads done before h2 (possibly == x) is written

    const float* bias = (m == 0) ? bq : (m == 1) ? bk : (m == 2) ? bv : bs;
    float* Op = (m == 0) ? q : (m == 1) ? k : (m == 2) ? v : o1;
#pragma unroll
    for (int nt = 0; nt < 8; ++nt) {
        float bvv = bias[nt * 16 + lrow];
#pragma unroll
        for (int mt = 0; mt < 2; ++mt) {
#pragma unroll
            for (int i = 0; i < 4; ++i) {
                int row = r0 + mt * 16 + lgrp * 4 + i;
                float val = acc[mt][nt][i] + bvv;
                size_t off = (size_t)row * DIM + nt * 16 + lrow;
                Op[off] = val;
                if (m == 3) h2[off] = val;
            }
        }
    }
}

// ---------------------------------------------------------------------------
// CSR build: histogram -> exclusive scan -> scatter.
__global__ __launch_bounds__(256) void hist_kernel(const int* __restrict__ ei,
                                                   int* __restrict__ deg) {
    int e = blockIdx.x * 256 + threadIdx.x;
    if (e < NEDGES) atomicAdd(&deg[ei[NEDGES + e]], 1);
}

__global__ __launch_bounds__(256) void scan1_kernel(const int* __restrict__ deg,
                                                    int* __restrict__ excl,
                                                    int* __restrict__ bsum) {
    __shared__ int s[256];
    const int tid = threadIdx.x;
    const int i = blockIdx.x * 256 + tid;
    const int v = (i < NNODES) ? deg[i] : 0;
    s[tid] = v;
    __syncthreads();
    for (int off = 1; off < 256; off <<= 1) {
        int t = (tid >= off) ? s[tid - off] : 0;
        __syncthreads();
        s[tid] += t;
        __syncthreads();
    }
    if (i < NNODES) excl[i] = s[tid] - v;
    if (tid == 255) bsum[blockIdx.x] = s[255];
}

__global__ __launch_bounds__(512) void scan2_kernel(int* __restrict__ bsum) {
    __shared__ int s[512];
    const int tid = threadIdx.x;
    const int v = (tid < NB1) ? bsum[tid] : 0;
    s[tid] = v;
    __syncthreads();
    for (int off = 1; off < 512; off <<= 1) {
        int t = (tid >= off) ? s[tid - off] : 0;
        __syncthreads();
        s[tid] += t;
        __syncthreads();
    }
    if (tid < NB1) bsum[tid] = s[tid] - v;   // exclusive
}

__global__ __launch_bounds__(256) void scan3_kernel(const int* __restrict__ excl,
                                                    const int* __restrict__ bsum,
                                                    int* __restrict__ rowptr) {
    const int i = blockIdx.x * 256 + threadIdx.x;
    if (i < NNODES) rowptr[i] = excl[i] + bsum[blockIdx.x];
    if (i == 0) rowptr[NNODES] = NEDGES;
}

__global__ __launch_bounds__(256) void scatter_edges_kernel(
    const int* __restrict__ ei, const int* __restrict__ rowptr,
    int* __restrict__ fill, int* __restrict__ ssrc, int* __restrict__ se) {
    int e = blockIdx.x * 256 + threadIdx.x;
    if (e >= NEDGES) return;
    int dst = ei[NEDGES + e];
    int pos = rowptr[dst] + atomicAdd(&fill[dst], 1);
    ssrc[pos] = ei[e];
    se[pos] = e;
}

// ---------------------------------------------------------------------------
// Fused edge phase: one wave per dst node, flash-style online softmax over
// its incoming edges. No atomics; out already holds the skip term.
__global__ __launch_bounds__(256) void attn_aggregate_kernel(
    const int* __restrict__ rowptr, const int* __restrict__ ssrc,
    const int* __restrict__ se, const float* __restrict__ ea,
    const float* __restrict__ we,
    const float* __restrict__ q, const float* __restrict__ k,
    const float* __restrict__ v, float* __restrict__ out)
{
    const int wave = threadIdx.x >> 6;
    const int lane = threadIdx.x & 63;
    const int d = blockIdx.x * 4 + wave;
    if (d >= NNODES) return;
    const int c0 = lane, c1 = lane + 64;
    const float w00 = we[c0 * 3 + 0], w01 = we[c0 * 3 + 1], w02 = we[c0 * 3 + 2];
    const float w10 = we[c1 * 3 + 0], w11 = we[c1 * 3 + 1], w12 = we[c1 * 3 + 2];
    const int p0 = rowptr[d], p1 = rowptr[d + 1];
    if (p0 == p1) return;
    const float scale = 0.08838834764831845f;   // 1/sqrt(128)
    const float q0 = q[(size_t)d * DIM + c0] * scale;
    const float q1 = q[(size_t)d * DIM + c1] * scale;
    float m = -INFINITY, den = 0.f, a0 = 0.f, a1 = 0.f;
    for (int p = p0; p < p1; ++p) {
        const int src = ssrc[p];
        const int e = se[p];
        const float ea0 = ea[e * 3 + 0], ea1 = ea[e * 3 + 1], ea2 = ea[e * 3 + 2];
        const float ep0 = fmaf(ea0, w00, fmaf(ea1, w01, ea2 * w02));
        const float ep1 = fmaf(ea0, w10, fmaf(ea1, w11, ea2 * w12));
        const float k0 = k[(size_t)src * DIM + c0] + ep0;
        const float k1 = k[(size_t)src * DIM + c1] + ep1;
        float l = fmaf(q0, k0, q1 * k1);
#pragma unroll
    for (int off = 32; off > 0; off >>= 1) l += __shfl_xor(l, off, 64);
        const float mn = fmaxf(m, l);
        const float sc = expf(m - mn);      // 0 on first edge (m = -inf)
        const float wE = expf(l - mn);
        den = den * sc + wE;
        const float v0 = v[(size_t)src * DIM + c0] + ep0;
        const float v1 = v[(size_t)src * DIM + c1] + ep1;
        a0 = fmaf(a0, sc, wE * v0);
        a1 = fmaf(a1, sc, wE * v1);
        m = mn;
    }
    const float inv = 1.f / (den + 1e-16f);
    out[(size_t)d * DIM + c0] += a0 * inv;
    out[(size_t)d * DIM + c1] += a1 * inv;
}

// h = relu(h) - relu(o1)   (in place)
__global__ __launch_bounds__(256) void combine_kernel(
    const float4* __restrict__ o1, float4* __restrict__ h)
{
    const int i = blockIdx.x * 256 + threadIdx.x;
    float4 a = o1[i];
    float4 b = h[i];
    float4 r;
    r.x = fmaxf(b.x, 0.f) - fmaxf(a.x, 0.f);
    r.y = fmaxf(b.y, 0.f) - fmaxf(a.y, 0.f);
    r.z = fmaxf(b.z, 0.f) - fmaxf(a.z, 0.f);
    r.w = fmaxf(b.w, 0.f) - fmaxf(a.w, 0.f);
    h[i] = r;
}

// Mean-pool prep: batchs sorted -> run accumulation, atomic flush per boundary.
__global__ __launch_bounds__(256) void pool_kernel(
    const float* __restrict__ h, const int* __restrict__ batchs,
    float* __restrict__ sums, float* __restrict__ cnt)
{
    const int sub = threadIdx.x >> 7;
    const int c = threadIdx.x & 127;
    int n0 = blockIdx.x * 32 + sub * 16;
    int nend = n0 + 16;
    if (nend > NNODES) nend = NNODES;
    float acc = 0.f, ccnt = 0.f;
    int curb = -1;
    for (int nd = n0; nd < nend; ++nd) {
        int b = batchs[nd];
        if (b != curb) {
            if (curb >= 0) {
                atomicAdd(&sums[curb * DIM + c], acc);
                if (c == 0) atomicAdd(&cnt[curb], ccnt);
            }
            acc = 0.f; ccnt = 0.f; curb = b;
        }
        acc += h[(size_t)nd * DIM + c];
        ccnt += 1.f;
    }
    if (curb >= 0) {
        atomicAdd(&sums[curb * DIM + c], acc);
        if (c == 0) atomicAdd(&cnt[curb], ccnt);
    }
}

// Whole MLP head per batch row.
__global__ __launch_bounds__(256) void head_kernel(
    const float* __restrict__ sums, const float* __restrict__ cnt,
    const float* __restrict__ l0w, const float* __restrict__ l0b,
    const float* __restrict__ l1w, const float* __restrict__ l1b,
    const float* __restrict__ l3w, const float* __restrict__ l3b,
    float* __restrict__ out)
{
    __shared__ float g[DIM];
    __shared__ float h0[DFC];
    __shared__ float h1[DFC];
    __shared__ float lg[2];
    const int b = blockIdx.x;
    const int tid = threadIdx.x;
    const float c = fmaxf(cnt[b], 1.0f);
    if (tid < DIM) g[tid] = sums[b * DIM + tid] / c;
    __syncthreads();
    for (int o = tid; o < DFC; o += 256) {
        float acc = l0b[o];
        for (int kk = 0; kk < DIM; ++kk) acc = fmaf(g[kk], l0w[o * DIM + kk], acc);
        h0[o] = fmaxf(acc, 0.f);
    }
    __syncthreads();
    for (int o = tid; o < DFC; o += 256) {
        float acc = l1b[o];
        for (int kk = 0; kk < DFC; ++kk) acc = fmaf(h0[kk], l1w[o * DFC + kk], acc);
        h1[o] = fmaxf(acc, 0.f);
    }
    __syncthreads();
    if (tid < 2) {
        float acc = l3b[tid];
        for (int kk = 0; kk < DFC; ++kk) acc = fmaf(h1[kk], l3w[tid * DFC + kk], acc);
        lg[tid] = acc;
    }
    __syncthreads();
    if (tid == 0) {
        float l0 = lg[0], l1v = lg[1];
        float mx = fmaxf(l0, l1v);
        float lse = mx + logf(expf(l0 - mx) + expf(l1v - mx));
        out[b * 2 + 0] = l0 - lse;
        out[b * 2 + 1] = l1v - lse;
    }
}

// ---------------------------------------------------------------------------
extern "C" void kernel_launch(void* const* d_in, const int* in_sizes, int n_in,
                              void* d_out, int out_size, void* d_ws, size_t ws_size,
                              hipStream_t stream)
{
    const float* x      = (const float*)d_in[0];
    const int*   ei1    = (const int*)d_in[1];
    const int*   ei2    = (const int*)d_in[2];
    const float* ea1    = (const float*)d_in[3];
    const float* ea2    = (const float*)d_in[4];
    const int*   batchs = (const int*)d_in[6];

    // workspace layout
    float* ws_f = (float*)d_ws;
    const size_t ND = (size_t)NNODES * DIM;
    float* q    = ws_f;
    float* kbuf = q + ND;
    float* v    = kbuf + ND;
    float* o1   = v + ND;
    float* h    = o1 + ND;                 // doubles as o2 and next-layer input
    float* sums = h + ND;
    float* cnt  = sums + NB * DIM;
    short* whi  = (short*)(cnt + NB);      // 16 mats * 16384 bf16 (hi)
    short* wlo  = whi + 16 * 16384;
    int*   ip   = (int*)(wlo + 16 * 16384);
    int* rowptr1 = ip;                     // N+1
    int* rowptr2 = rowptr1 + (NNODES + 1);
    int* ssrc1   = rowptr2 + (NNODES + 1); // E
    int* se1     = ssrc1 + NEDGES;
    int* ssrc2   = se1 + NEDGES;
    int* se2     = ssrc2 + NEDGES;
    int* deg     = se2 + NEDGES;           // N temp
    int* excl    = deg + NNODES;           // N temp (reused as fill)
    int* bsum    = excl + NNODES;          // 512 temp

    // ---- Split all layer weights into bf16 hi/lo frag-major, once ----
    wsplit_kernel<<<128, 256, 0, stream>>>(
        (const float*)d_in[7], (const float*)d_in[9],
        (const float*)d_in[11], (const float*)d_in[14],
        (const float*)d_in[16], (const float*)d_in[18],
        (const float*)d_in[20], (const float*)d_in[23],
        whi, wlo);

    // ---- Build CSR (dst-sorted) for both edge sets ----
    for (int gi = 0; gi < 2; ++gi) {
        const int* ei = gi ? ei2 : ei1;
        int* rowptr = gi ? rowptr2 : rowptr1;
        int* ssrc   = gi ? ssrc2 : ssrc1;
        int* se     = gi ? se2 : se1;
        hipMemsetAsync(deg, 0, NNODES * sizeof(int), stream);
        hist_kernel<<<(NEDGES + 255) / 256, 256, 0, stream>>>(ei, deg);
        scan1_kernel<<<NB1, 256, 0, stream>>>(deg, excl, bsum);
        scan2_kernel<<<1, 512, 0, stream>>>(bsum);
        scan3_kernel<<<NB1, 256, 0, stream>>>(excl, bsum, rowptr);
        hipMemsetAsync(excl, 0, NNODES * sizeof(int), stream);   // reuse as fill
        scatter_edges_kernel<<<(NEDGES + 255) / 256, 256, 0, stream>>>(ei, rowptr, excl, ssrc, se);
    }

    // ---- Layers ----
    const float* xin = x;
    for (int li = 0; li < 4; ++li) {
        const float *bq_, *bk_, *bv_, *bs_, *we_;
        if (li == 0) {
            bq_ = (const float*)d_in[8];
            bk_ = (const float*)d_in[10];
            bv_ = (const float*)d_in[12];
            bs_ = (const float*)d_in[15];
            we_ = (const float*)d_in[13];
        } else {
            int i = li - 1;
            bq_ = (const float*)d_in[17] + (size_t)i * DIM;
            bk_ = (const float*)d_in[19] + (size_t)i * DIM;
            bv_ = (const float*)d_in[21] + (size_t)i * DIM;
            bs_ = (const float*)d_in[24] + (size_t)i * DIM;
            we_ = (const float*)d_in[22] + (size_t)i * DIM * 3;
        }

        qkvs_mfma_kernel<<<NNODES / 32, 256, 0, stream>>>(
            xin, whi + (size_t)li * 4 * 16384, wlo + (size_t)li * 4 * 16384,
            bq_, bk_, bv_, bs_, q, kbuf, v, o1, h);

        attn_aggregate_kernel<<<(NNODES + 3) / 4, 256, 0, stream>>>(
            rowptr1, ssrc1, se1, ea1, we_, q, kbuf, v, o1);
        attn_aggregate_kernel<<<(NNODES + 3) / 4, 256, 0, stream>>>(
            rowptr2, ssrc2, se2, ea2, we_, q, kbuf, v, h);

        combine_kernel<<<(int)(ND / 1024), 256, 0, stream>>>((const float4*)o1, (float4*)h);
        xin = h;
    }

    hipMemsetAsync(sums, 0, NB * DIM * sizeof(float), stream);
    hipMemsetAsync(cnt, 0, NB * sizeof(float), stream);
    pool_kernel<<<(NNODES + 31) / 32, 256, 0, stream>>>(h, batchs, sums, cnt);
    head_kernel<<<NB, 256, 0, stream>>>(sums, cnt,
        (const float*)d_in[25], (const float*)d_in[26],
        (const float*)d_in[27], (const float*)d_in[28],
        (const float*)d_in[29], (const float*)d_in[30],
        (float*)d_out);
}

// Round 9
// 1900.130 us; speedup vs baseline: 2.4673x; 1.0541x over previous
//
#include <hip/hip_runtime.h>

#define NNODES 100000
#define NEDGES 600000
#define DIM    128
#define NB     64
#define DFC    512
#define NB1    391   // ceil(NNODES/256) blocks for the scan

typedef __attribute__((ext_vector_type(8))) short short8v;
typedef __attribute__((ext_vector_type(4))) float float4v;

// ---------------------------------------------------------------------------
// Split all 16 layer weight matrices into bf16 hi/lo, stored MFMA-frag-major.
__global__ __launch_bounds__(256) void wsplit_kernel(
    const float* __restrict__ c1q, const float* __restrict__ c1k,
    const float* __restrict__ c1v, const float* __restrict__ c1s,
    const float* __restrict__ csq, const float* __restrict__ csk,
    const float* __restrict__ csv, const float* __restrict__ css,
    short* __restrict__ whi, short* __restrict__ wlo)
{
    int t = blockIdx.x * 256 + threadIdx.x;     // 0..32767
    int mat = t >> 11;                          // 0..15
    int tt = t & 2047;
    int lane = tt & 63, nt = (tt >> 6) & 7, ks = tt >> 9;
    int li = mat >> 2, mm = mat & 3;
    const float* W;
    if (li == 0) W = (mm == 0) ? c1q : (mm == 1) ? c1k : (mm == 2) ? c1v : c1s;
    else {
        const float* base = (mm == 0) ? csq : (mm == 1) ? csk : (mm == 2) ? csv : css;
        W = base + (size_t)(li - 1) * 16384;
    }
    int n = nt * 16 + (lane & 15);
    int k0 = ks * 32 + (lane >> 4) * 8;
    size_t ob = (size_t)mat * 16384 + (size_t)((ks * 8 + nt) * 64 + lane) * 8;
#pragma unroll
    for (int j = 0; j < 8; ++j) {
        float w = W[n * 128 + k0 + j];
        unsigned ub = __float_as_uint(w);
        float lo = w - __uint_as_float(ub & 0xFFFF0000u);
        whi[ob + j] = (short)(ub >> 16);
        wlo[ob + j] = (short)(__float_as_uint(lo) >> 16);
    }
}

// ---------------------------------------------------------------------------
// Split-bf16 MFMA fused q/k/v/skip GEMM (unchanged from round 4, passed).
__global__ __launch_bounds__(256) void qkvs_mfma_kernel(
    const float* __restrict__ x,
    const short* __restrict__ whi, const short* __restrict__ wlo,
    const float* __restrict__ bq, const float* __restrict__ bk,
    const float* __restrict__ bv, const float* __restrict__ bs,
    float* __restrict__ q, float* __restrict__ k, float* __restrict__ v,
    float* __restrict__ o1, float* __restrict__ h2)
{
    const int lane = threadIdx.x & 63;
    const int m = threadIdx.x >> 6;
    const int r0 = blockIdx.x * 32;
    const int lrow = lane & 15;
    const int lgrp = lane >> 4;

    float4v acc[2][8] = {};
    const short* Whi = whi + (size_t)m * 16384;
    const short* Wlo = wlo + (size_t)m * 16384;

    for (int ks = 0; ks < 4; ++ks) {
        short8v ahi[2], alo[2];
#pragma unroll
        for (int mt = 0; mt < 2; ++mt) {
            const float* xp = x + (size_t)(r0 + mt * 16 + lrow) * DIM + ks * 32 + lgrp * 8;
            float4 xa = *(const float4*)xp;
            float4 xb = *(const float4*)(xp + 4);
            float xs[8] = {xa.x, xa.y, xa.z, xa.w, xb.x, xb.y, xb.z, xb.w};
#pragma unroll
            for (int j = 0; j < 8; ++j) {
                unsigned ub = __float_as_uint(xs[j]);
                float lo = xs[j] - __uint_as_float(ub & 0xFFFF0000u);
                ahi[mt][j] = (short)(ub >> 16);
                alo[mt][j] = (short)(__float_as_uint(lo) >> 16);
            }
        }
        const short* bh = Whi + (size_t)((ks * 8) * 64 + lane) * 8;
        const short* bl = Wlo + (size_t)((ks * 8) * 64 + lane) * 8;
#pragma unroll
        for (int nt = 0; nt < 8; ++nt) {
            short8v bhi = *(const short8v*)(bh + (size_t)nt * 512);
            short8v blo = *(const short8v*)(bl + (size_t)nt * 512);
#pragma unroll
            for (int mt = 0; mt < 2; ++mt) {
                acc[mt][nt] = __builtin_amdgcn_mfma_f32_16x16x32_bf16(ahi[mt], bhi, acc[mt][nt], 0, 0, 0);
                acc[mt][nt] = __builtin_amdgcn_mfma_f32_16x16x32_bf16(ahi[mt], blo, acc[mt][nt], 0, 0, 0);
                acc[mt][nt] = __builtin_amdgcn_mfma_f32_16x16x32_bf16(alo[mt], bhi, acc[mt][nt], 0, 0, 0);
            }
        }
    }

    __syncthreads();   // all x reads done before h2 (possibly == x) is written

    const float* bias = (m == 0) ? bq : (m == 1) ? bk : (m == 2) ? bv : bs;
    float* Op = (m == 0) ? q : (m == 1) ? k : (m == 2) ? v : o1;
#pragma unroll
    for (int nt = 0; nt < 8; ++nt) {
        float bvv = bias[nt * 16 + lrow];
#pragma unroll
        for (int mt = 0; mt < 2; ++mt) {
#pragma unroll
            for (int i = 0; i < 4; ++i) {
                int row = r0 + mt * 16 + lgrp * 4 + i;
                float val = acc[mt][nt][i] + bvv;
                size_t off = (size_t)row * DIM + nt * 16 + lrow;
                Op[off] = val;
                if (m == 3) h2[off] = val;
            }
        }
    }
}

// ---------------------------------------------------------------------------
// CSR build: histogram -> exclusive scan -> scatter of (src, edge_id) int2.
__global__ __launch_bounds__(256) void hist_kernel(const int* __restrict__ ei,
                                                   int* __restrict__ deg) {
    int e = blockIdx.x * 256 + threadIdx.x;
    if (e < NEDGES) atomicAdd(&deg[ei[NEDGES + e]], 1);
}

__global__ __launch_bounds__(256) void scan1_kernel(const int* __restrict__ deg,
                                                    int* __restrict__ excl,
                                                    int* __restrict__ bsum) {
    __shared__ int s[256];
    const int tid = threadIdx.x;
    const int i = blockIdx.x * 256 + tid;
    const int v = (i < NNODES) ? deg[i] : 0;
    s[tid] = v;
    __syncthreads();
    for (int off = 1; off < 256; off <<= 1) {
        int t = (tid >= off) ? s[tid - off] : 0;
        __syncthreads();
        s[tid] += t;
        __syncthreads();
    }
    if (i < NNODES) excl[i] = s[tid] - v;
    if (tid == 255) bsum[blockIdx.x] = s[255];
}

__global__ __launch_bounds__(512) void scan2_kernel(int* __restrict__ bsum) {
    __shared__ int s[512];
    const int tid = threadIdx.x;
    const int v = (tid < NB1) ? bsum[tid] : 0;
    s[tid] = v;
    __syncthreads();
    for (int off = 1; off < 512; off <<= 1) {
        int t = (tid >= off) ? s[tid - off] : 0;
        __syncthreads();
        s[tid] += t;
        __syncthreads();
    }
    if (tid < NB1) bsum[tid] = s[tid] - v;   // exclusive
}

__global__ __launch_bounds__(256) void scan3_kernel(const int* __restrict__ excl,
                                                    const int* __restrict__ bsum,
                                                    int* __restrict__ rowptr) {
    const int i = blockIdx.x * 256 + threadIdx.x;
    if (i < NNODES) rowptr[i] = excl[i] + bsum[blockIdx.x];
    if (i == 0) rowptr[NNODES] = NEDGES;
}

__global__ __launch_bounds__(256) void scatter_edges_kernel(
    const int* __restrict__ ei, const int* __restrict__ rowptr,
    int* __restrict__ fill, int2* __restrict__ sse) {
    int e = blockIdx.x * 256 + threadIdx.x;
    if (e >= NEDGES) return;
    int dst = ei[NEDGES + e];
    int pos = rowptr[dst] + atomicAdd(&fill[dst], 1);
    sse[pos] = make_int2(ei[e], e);
}

// ---------------------------------------------------------------------------
// Fused edge phase, BOTH graphs in one launch. One wave per (graph, dst):
// chunk-4 edges per iteration — 4 independent (src,e) int2 loads + dependent
// ea gathers + k/v row gathers, interleaved wave reduces, ONE merged
// online-softmax update. No atomics.
__global__ __launch_bounds__(256) void attn_aggregate_kernel(
    const int* __restrict__ rowptr1, const int2* __restrict__ sse1,
    const float* __restrict__ ea1,
    const int* __restrict__ rowptr2, const int2* __restrict__ sse2,
    const float* __restrict__ ea2,
    const float* __restrict__ we,
    const float* __restrict__ q, const float* __restrict__ k,
    const float* __restrict__ v,
    float* __restrict__ o1, float* __restrict__ o2)
{
    const int wave = threadIdx.x >> 6;
    const int lane = threadIdx.x & 63;
    const int idx = blockIdx.x * 4 + wave;        // [0, 2*NNODES)
    if (idx >= 2 * NNODES) return;
    const int g = (idx >= NNODES) ? 1 : 0;
    const int d = idx - (g ? NNODES : 0);

    const int*   rowptr = g ? rowptr2 : rowptr1;
    const int2*  sse    = g ? sse2 : sse1;
    const float* ea     = g ? ea2 : ea1;
    float*       out    = g ? o2 : o1;

    const int p0 = rowptr[d], p1 = rowptr[d + 1];
    if (p0 == p1) return;

    const int c0 = lane, c1 = lane + 64;
    const float w00 = we[c0 * 3 + 0], w01 = we[c0 * 3 + 1], w02 = we[c0 * 3 + 2];
    const float w10 = we[c1 * 3 + 0], w11 = we[c1 * 3 + 1], w12 = we[c1 * 3 + 2];
    const float scale = 0.08838834764831845f;   // 1/sqrt(128)
    const float q0 = q[(size_t)d * DIM + c0] * scale;
    const float q1 = q[(size_t)d * DIM + c1] * scale;

    float m = -INFINITY, den = 0.f, a0 = 0.f, a1 = 0.f;

    for (int p = p0; p < p1; p += 4) {
        const int nn = p1 - p;                   // wave-uniform
        float l[4], vv0[4], vv1[4];
#pragma unroll
        for (int j = 0; j < 4; ++j) {
            if (j < nn) {
                const int2 sv = sse[p + j];
                const int src = sv.x;
                const float ea0 = ea[sv.y * 3 + 0];
                const float ea1v = ea[sv.y * 3 + 1];
                const float ea2v = ea[sv.y * 3 + 2];
                const float ep0 = fmaf(ea0, w00, fmaf(ea1v, w01, ea2v * w02));
                const float ep1 = fmaf(ea0, w10, fmaf(ea1v, w11, ea2v * w12));
                const float* kp = k + (size_t)src * DIM;
                const float* vp = v + (size_t)src * DIM;
                const float k0 = kp[c0] + ep0;
                const float k1 = kp[c1] + ep1;
                vv0[j] = vp[c0] + ep0;
                vv1[j] = vp[c1] + ep1;
                l[j] = fmaf(q0, k0, q1 * k1);
            } else {
                l[j] = -INFINITY;
                vv0[j] = 0.f;
                vv1[j] = 0.f;
            }
        }
        // 4 interleaved wave reduces (chain depth 6, width 4)
#pragma unroll
        for (int off = 32; off > 0; off >>= 1) {
#pragma unroll
            for (int j = 0; j < 4; ++j) l[j] += __shfl_xor(l[j], off, 64);
        }
        // merged online-softmax update (exp(-inf - mn) == 0 for pad slots)
        const float cm = fmaxf(fmaxf(l[0], l[1]), fmaxf(l[2], l[3]));
        const float mn = fmaxf(m, cm);
        const float sc = __expf(m - mn);        // 0 on first chunk (m = -inf)
        const float e0 = __expf(l[0] - mn), e1 = __expf(l[1] - mn);
        const float e2 = __expf(l[2] - mn), e3 = __expf(l[3] - mn);
        den = den * sc + ((e0 + e1) + (e2 + e3));
        a0 = a0 * sc + ((e0 * vv0[0] + e1 * vv0[1]) + (e2 * vv0[2] + e3 * vv0[3]));
        a1 = a1 * sc + ((e0 * vv1[0] + e1 * vv1[1]) + (e2 * vv1[2] + e3 * vv1[3]));
        m = mn;
    }
    const float inv = 1.f / (den + 1e-16f);
    out[(size_t)d * DIM + c0] += a0 * inv;
    out[(size_t)d * DIM + c1] += a1 * inv;
}

// h = relu(h) - relu(o1)   (in place)
__global__ __launch_bounds__(256) void combine_kernel(
    const float4* __restrict__ o1, float4* __restrict__ h)
{
    const int i = blockIdx.x * 256 + threadIdx.x;
    float4 a = o1[i];
    float4 b = h[i];
    float4 r;
    r.x = fmaxf(b.x, 0.f) - fmaxf(a.x, 0.f);
    r.y = fmaxf(b.y, 0.f) - fmaxf(a.y, 0.f);
    r.z = fmaxf(b.z, 0.f) - fmaxf(a.z, 0.f);
    r.w = fmaxf(b.w, 0.f) - fmaxf(a.w, 0.f);
    h[i] = r;
}

// Mean-pool prep: batchs sorted -> run accumulation, atomic flush per boundary.
__global__ __launch_bounds__(256) void pool_kernel(
    const float* __restrict__ h, const int* __restrict__ batchs,
    float* __restrict__ sums, float* __restrict__ cnt)
{
    const int sub = threadIdx.x >> 7;
    const int c = threadIdx.x & 127;
    int n0 = blockIdx.x * 32 + sub * 16;
    int nend = n0 + 16;
    if (nend > NNODES) nend = NNODES;
    float acc = 0.f, ccnt = 0.f;
    int curb = -1;
    for (int nd = n0; nd < nend; ++nd) {
        int b = batchs[nd];
        if (b != curb) {
            if (curb >= 0) {
                atomicAdd(&sums[curb * DIM + c], acc);
                if (c == 0) atomicAdd(&cnt[curb], ccnt);
            }
            acc = 0.f; ccnt = 0.f; curb = b;
        }
        acc += h[(size_t)nd * DIM + c];
        ccnt += 1.f;
    }
    if (curb >= 0) {
        atomicAdd(&sums[curb * DIM + c], acc);
        if (c == 0) atomicAdd(&cnt[curb], ccnt);
    }
}

// Whole MLP head per batch row.
__global__ __launch_bounds__(256) void head_kernel(
    const float* __restrict__ sums, const float* __restrict__ cnt,
    const float* __restrict__ l0w, const float* __restrict__ l0b,
    const float* __restrict__ l1w, const float* __restrict__ l1b,
    const float* __restrict__ l3w, const float* __restrict__ l3b,
    float* __restrict__ out)
{
    __shared__ float g[DIM];
    __shared__ float h0[DFC];
    __shared__ float h1[DFC];
    __shared__ float lg[2];
    const int b = blockIdx.x;
    const int tid = threadIdx.x;
    const float c = fmaxf(cnt[b], 1.0f);
    if (tid < DIM) g[tid] = sums[b * DIM + tid] / c;
    __syncthreads();
    for (int o = tid; o < DFC; o += 256) {
        float acc = l0b[o];
        for (int kk = 0; kk < DIM; ++kk) acc = fmaf(g[kk], l0w[o * DIM + kk], acc);
        h0[o] = fmaxf(acc, 0.f);
    }
    __syncthreads();
    for (int o = tid; o < DFC; o += 256) {
        float acc = l1b[o];
        for (int kk = 0; kk < DFC; ++kk) acc = fmaf(h0[kk], l1w[o * DFC + kk], acc);
        h1[o] = fmaxf(acc, 0.f);
    }
    __syncthreads();
    if (tid < 2) {
        float acc = l3b[tid];
        for (int kk = 0; kk < DFC; ++kk) acc = fmaf(h1[kk], l3w[tid * DFC + kk], acc);
        lg[tid] = acc;
    }
    __syncthreads();
    if (tid == 0) {
        float l0 = lg[0], l1v = lg[1];
        float mx = fmaxf(l0, l1v);
        float lse = mx + logf(expf(l0 - mx) + expf(l1v - mx));
        out[b * 2 + 0] = l0 - lse;
        out[b * 2 + 1] = l1v - lse;
    }
}

// ---------------------------------------------------------------------------
extern "C" void kernel_launch(void* const* d_in, const int* in_sizes, int n_in,
                              void* d_out, int out_size, void* d_ws, size_t ws_size,
                              hipStream_t stream)
{
    const float* x      = (const float*)d_in[0];
    const int*   ei1    = (const int*)d_in[1];
    const int*   ei2    = (const int*)d_in[2];
    const float* ea1    = (const float*)d_in[3];
    const float* ea2    = (const float*)d_in[4];
    const int*   batchs = (const int*)d_in[6];

    // workspace layout — total 268,283,656 B, must stay <= 256 MiB (268,435,456)
    float* ws_f = (float*)d_ws;
    const size_t ND = (size_t)NNODES * DIM;
    float* q    = ws_f;
    float* kbuf = q + ND;
    float* v    = kbuf + ND;
    float* o1   = v + ND;
    float* h    = o1 + ND;                 // doubles as o2 and next-layer input
    float* sums = h + ND;
    float* cnt  = sums + NB * DIM;
    short* whi  = (short*)(cnt + NB);      // 16 mats * 16384 bf16 (hi)
    short* wlo  = whi + 16 * 16384;
    int*   ip   = (int*)(wlo + 16 * 16384);
    int*  rowptr1 = ip;                    // N+1
    int*  rowptr2 = rowptr1 + (NNODES + 1);
    int2* sse1    = (int2*)(rowptr2 + (NNODES + 1));  // E int2 (src, edge_id)
    int2* sse2    = sse1 + NEDGES;
    int*  deg     = (int*)(sse2 + NEDGES); // N temp
    int*  excl    = deg + NNODES;          // N temp (reused as fill)
    int*  bsum    = excl + NNODES;         // 512 temp

    // ---- Split all layer weights into bf16 hi/lo frag-major, once ----
    wsplit_kernel<<<128, 256, 0, stream>>>(
        (const float*)d_in[7], (const float*)d_in[9],
        (const float*)d_in[11], (const float*)d_in[14],
        (const float*)d_in[16], (const float*)d_in[18],
        (const float*)d_in[20], (const float*)d_in[23],
        whi, wlo);

    // ---- Build CSR (dst-sorted) for both edge sets ----
    for (int gi = 0; gi < 2; ++gi) {
        const int* ei = gi ? ei2 : ei1;
        int*  rowptr = gi ? rowptr2 : rowptr1;
        int2* sse    = gi ? sse2 : sse1;
        hipMemsetAsync(deg, 0, NNODES * sizeof(int), stream);
        hist_kernel<<<(NEDGES + 255) / 256, 256, 0, stream>>>(ei, deg);
        scan1_kernel<<<NB1, 256, 0, stream>>>(deg, excl, bsum);
        scan2_kernel<<<1, 512, 0, stream>>>(bsum);
        scan3_kernel<<<NB1, 256, 0, stream>>>(excl, bsum, rowptr);
        hipMemsetAsync(excl, 0, NNODES * sizeof(int), stream);   // reuse as fill
        scatter_edges_kernel<<<(NEDGES + 255) / 256, 256, 0, stream>>>(ei, rowptr, excl, sse);
    }

    // ---- Layers ----
    const float* xin = x;
    for (int li = 0; li < 4; ++li) {
        const float *bq_, *bk_, *bv_, *bs_, *we_;
        if (li == 0) {
            bq_ = (const float*)d_in[8];
            bk_ = (const float*)d_in[10];
            bv_ = (const float*)d_in[12];
            bs_ = (const float*)d_in[15];
            we_ = (const float*)d_in[13];
        } else {
            int i = li - 1;
            bq_ = (const float*)d_in[17] + (size_t)i * DIM;
            bk_ = (const float*)d_in[19] + (size_t)i * DIM;
            bv_ = (const float*)d_in[21] + (size_t)i * DIM;
            bs_ = (const float*)d_in[24] + (size_t)i * DIM;
            we_ = (const float*)d_in[22] + (size_t)i * DIM * 3;
        }

        qkvs_mfma_kernel<<<NNODES / 32, 256, 0, stream>>>(
            xin, whi + (size_t)li * 4 * 16384, wlo + (size_t)li * 4 * 16384,
            bq_, bk_, bv_, bs_, q, kbuf, v, o1, h);

        attn_aggregate_kernel<<<(2 * NNODES + 3) / 4, 256, 0, stream>>>(
            rowptr1, sse1, ea1, rowptr2, sse2, ea2,
            we_, q, kbuf, v, o1, h);

        combine_kernel<<<(int)(ND / 1024), 256, 0, stream>>>((const float4*)o1, (float4*)h);
        xin = h;
    }

    hipMemsetAsync(sums, 0, NB * DIM * sizeof(float), stream);
    hipMemsetAsync(cnt, 0, NB * sizeof(float), stream);
    pool_kernel<<<(NNODES + 31) / 32, 256, 0, stream>>>(h, batchs, sums, cnt);
    head_kernel<<<NB, 256, 0, stream>>>(sums, cnt,
        (const float*)d_in[25], (const float*)d_in[26],
        (const float*)d_in[27], (const float*)d_in[28],
        (const float*)d_in[29], (const float*)d_in[30],
        (float*)d_out);
}

// Round 10
// 1814.397 us; speedup vs baseline: 2.5839x; 1.0473x over previous
//
#include <hip/hip_runtime.h>

#define NNODES 100000
#define NEDGES 600000
#define DIM    128
#define NB     64
#define DFC    512
#define NB1    391   // ceil(NNODES/256) blocks for the scan

typedef __attribute__((ext_vector_type(8))) short short8v;
typedef __attribute__((ext_vector_type(4))) float float4v;

__device__ __forceinline__ float bf2f(unsigned short u) {
    return __uint_as_float((unsigned)u << 16);
}
__device__ __forceinline__ unsigned short f2bf(float f) {
    unsigned u = __float_as_uint(f);
    return (unsigned short)((u + 0x7FFF + ((u >> 16) & 1)) >> 16);   // RNE
}

// ---------------------------------------------------------------------------
// Split all 16 layer weight matrices into bf16 hi/lo, stored MFMA-frag-major.
__global__ __launch_bounds__(256) void wsplit_kernel(
    const float* __restrict__ c1q, const float* __restrict__ c1k,
    const float* __restrict__ c1v, const float* __restrict__ c1s,
    const float* __restrict__ csq, const float* __restrict__ csk,
    const float* __restrict__ csv, const float* __restrict__ css,
    short* __restrict__ whi, short* __restrict__ wlo)
{
    int t = blockIdx.x * 256 + threadIdx.x;     // 0..32767
    int mat = t >> 11;                          // 0..15
    int tt = t & 2047;
    int lane = tt & 63, nt = (tt >> 6) & 7, ks = tt >> 9;
    int li = mat >> 2, mm = mat & 3;
    const float* W;
    if (li == 0) W = (mm == 0) ? c1q : (mm == 1) ? c1k : (mm == 2) ? c1v : c1s;
    else {
        const float* base = (mm == 0) ? csq : (mm == 1) ? csk : (mm == 2) ? csv : css;
        W = base + (size_t)(li - 1) * 16384;
    }
    int n = nt * 16 + (lane & 15);
    int k0 = ks * 32 + (lane >> 4) * 8;
    size_t ob = (size_t)mat * 16384 + (size_t)((ks * 8 + nt) * 64 + lane) * 8;
#pragma unroll
    for (int j = 0; j < 8; ++j) {
        float w = W[n * 128 + k0 + j];
        unsigned ub = __float_as_uint(w);
        float lo = w - __uint_as_float(ub & 0xFFFF0000u);
        whi[ob + j] = (short)(ub >> 16);
        wlo[ob + j] = (short)(__float_as_uint(lo) >> 16);
    }
}

// ---------------------------------------------------------------------------
// Split-bf16 MFMA fused q/k/v/skip GEMM. q and skip stored f32; k and v
// stored bf16 (RNE) — halves the attn gather working set so it L3-resides.
// Safe when x == h2: __syncthreads() before epilogue.
__global__ __launch_bounds__(256) void qkvs_mfma_kernel(
    const float* __restrict__ x,
    const short* __restrict__ whi, const short* __restrict__ wlo,
    const float* __restrict__ bq, const float* __restrict__ bk,
    const float* __restrict__ bv, const float* __restrict__ bs,
    float* __restrict__ q, unsigned short* __restrict__ k16,
    unsigned short* __restrict__ v16,
    float* __restrict__ o1, float* __restrict__ h2)
{
    const int lane = threadIdx.x & 63;
    const int m = threadIdx.x >> 6;
    const int r0 = blockIdx.x * 32;
    const int lrow = lane & 15;
    const int lgrp = lane >> 4;

    float4v acc[2][8] = {};
    const short* Whi = whi + (size_t)m * 16384;
    const short* Wlo = wlo + (size_t)m * 16384;

    for (int ks = 0; ks < 4; ++ks) {
        short8v ahi[2], alo[2];
#pragma unroll
        for (int mt = 0; mt < 2; ++mt) {
            const float* xp = x + (size_t)(r0 + mt * 16 + lrow) * DIM + ks * 32 + lgrp * 8;
            float4 xa = *(const float4*)xp;
            float4 xb = *(const float4*)(xp + 4);
            float xs[8] = {xa.x, xa.y, xa.z, xa.w, xb.x, xb.y, xb.z, xb.w};
#pragma unroll
            for (int j = 0; j < 8; ++j) {
                unsigned ub = __float_as_uint(xs[j]);
                float lo = xs[j] - __uint_as_float(ub & 0xFFFF0000u);
                ahi[mt][j] = (short)(ub >> 16);
                alo[mt][j] = (short)(__float_as_uint(lo) >> 16);
            }
        }
        const short* bh = Whi + (size_t)((ks * 8) * 64 + lane) * 8;
        const short* bl = Wlo + (size_t)((ks * 8) * 64 + lane) * 8;
#pragma unroll
        for (int nt = 0; nt < 8; ++nt) {
            short8v bhi = *(const short8v*)(bh + (size_t)nt * 512);
            short8v blo = *(const short8v*)(bl + (size_t)nt * 512);
#pragma unroll
            for (int mt = 0; mt < 2; ++mt) {
                acc[mt][nt] = __builtin_amdgcn_mfma_f32_16x16x32_bf16(ahi[mt], bhi, acc[mt][nt], 0, 0, 0);
                acc[mt][nt] = __builtin_amdgcn_mfma_f32_16x16x32_bf16(ahi[mt], blo, acc[mt][nt], 0, 0, 0);
                acc[mt][nt] = __builtin_amdgcn_mfma_f32_16x16x32_bf16(alo[mt], bhi, acc[mt][nt], 0, 0, 0);
            }
        }
    }

    __syncthreads();   // all x reads done before h2 (possibly == x) is written

    const float* bias = (m == 0) ? bq : (m == 1) ? bk : (m == 2) ? bv : bs;
#pragma unroll
    for (int nt = 0; nt < 8; ++nt) {
        float bvv = bias[nt * 16 + lrow];
#pragma unroll
        for (int mt = 0; mt < 2; ++mt) {
#pragma unroll
            for (int i = 0; i < 4; ++i) {
                int row = r0 + mt * 16 + lgrp * 4 + i;
                float val = acc[mt][nt][i] + bvv;
                size_t off = (size_t)row * DIM + nt * 16 + lrow;
                if (m == 0) q[off] = val;
                else if (m == 1) k16[off] = f2bf(val);
                else if (m == 2) v16[off] = f2bf(val);
                else { o1[off] = val; h2[off] = val; }
            }
        }
    }
}

// ---------------------------------------------------------------------------
// CSR build: histogram -> exclusive scan -> scatter of (src, edge_id) int2.
__global__ __launch_bounds__(256) void hist_kernel(const int* __restrict__ ei,
                                                   int* __restrict__ deg) {
    int e = blockIdx.x * 256 + threadIdx.x;
    if (e < NEDGES) atomicAdd(&deg[ei[NEDGES + e]], 1);
}

__global__ __launch_bounds__(256) void scan1_kernel(const int* __restrict__ deg,
                                                    int* __restrict__ excl,
                                                    int* __restrict__ bsum) {
    __shared__ int s[256];
    const int tid = threadIdx.x;
    const int i = blockIdx.x * 256 + tid;
    const int v = (i < NNODES) ? deg[i] : 0;
    s[tid] = v;
    __syncthreads();
    for (int off = 1; off < 256; off <<= 1) {
        int t = (tid >= off) ? s[tid - off] : 0;
        __syncthreads();
        s[tid] += t;
        __syncthreads();
    }
    if (i < NNODES) excl[i] = s[tid] - v;
    if (tid == 255) bsum[blockIdx.x] = s[255];
}

__global__ __launch_bounds__(512) void scan2_kernel(int* __restrict__ bsum) {
    __shared__ int s[512];
    const int tid = threadIdx.x;
    const int v = (tid < NB1) ? bsum[tid] : 0;
    s[tid] = v;
    __syncthreads();
    for (int off = 1; off < 512; off <<= 1) {
        int t = (tid >= off) ? s[tid - off] : 0;
        __syncthreads();
        s[tid] += t;
        __syncthreads();
    }
    if (tid < NB1) bsum[tid] = s[tid] - v;   // exclusive
}

__global__ __launch_bounds__(256) void scan3_kernel(const int* __restrict__ excl,
                                                    const int* __restrict__ bsum,
                                                    int* __restrict__ rowptr) {
    const int i = blockIdx.x * 256 + threadIdx.x;
    if (i < NNODES) rowptr[i] = excl[i] + bsum[blockIdx.x];
    if (i == 0) rowptr[NNODES] = NEDGES;
}

__global__ __launch_bounds__(256) void scatter_edges_kernel(
    const int* __restrict__ ei, const int* __restrict__ rowptr,
    int* __restrict__ fill, int2* __restrict__ sse) {
    int e = blockIdx.x * 256 + threadIdx.x;
    if (e >= NEDGES) return;
    int dst = ei[NEDGES + e];
    int pos = rowptr[dst] + atomicAdd(&fill[dst], 1);
    sse[pos] = make_int2(ei[e], e);
}

// ---------------------------------------------------------------------------
// Fused edge phase, BOTH graphs in one launch. One wave per (graph, dst):
// chunk-4 edges, bf16 k/v gathers (L3-resident), merged online-softmax.
__global__ __launch_bounds__(256) void attn_aggregate_kernel(
    const int* __restrict__ rowptr1, const int2* __restrict__ sse1,
    const float* __restrict__ ea1,
    const int* __restrict__ rowptr2, const int2* __restrict__ sse2,
    const float* __restrict__ ea2,
    const float* __restrict__ we,
    const float* __restrict__ q, const unsigned short* __restrict__ k16,
    const unsigned short* __restrict__ v16,
    float* __restrict__ o1, float* __restrict__ o2)
{
    const int wave = threadIdx.x >> 6;
    const int lane = threadIdx.x & 63;
    const int idx = blockIdx.x * 4 + wave;        // [0, 2*NNODES)
    if (idx >= 2 * NNODES) return;
    const int g = (idx >= NNODES) ? 1 : 0;
    const int d = idx - (g ? NNODES : 0);

    const int*   rowptr = g ? rowptr2 : rowptr1;
    const int2*  sse    = g ? sse2 : sse1;
    const float* ea     = g ? ea2 : ea1;
    float*       out    = g ? o2 : o1;

    const int p0 = rowptr[d], p1 = rowptr[d + 1];
    if (p0 == p1) return;

    const int c0 = lane, c1 = lane + 64;
    const float w00 = we[c0 * 3 + 0], w01 = we[c0 * 3 + 1], w02 = we[c0 * 3 + 2];
    const float w10 = we[c1 * 3 + 0], w11 = we[c1 * 3 + 1], w12 = we[c1 * 3 + 2];
    const float scale = 0.08838834764831845f;   // 1/sqrt(128)
    const float q0 = q[(size_t)d * DIM + c0] * scale;
    const float q1 = q[(size_t)d * DIM + c1] * scale;

    float m = -INFINITY, den = 0.f, a0 = 0.f, a1 = 0.f;

    for (int p = p0; p < p1; p += 4) {
        const int nn = p1 - p;                   // wave-uniform
        float l[4], vv0[4], vv1[4];
#pragma unroll
        for (int j = 0; j < 4; ++j) {
            if (j < nn) {
                const int2 sv = sse[p + j];
                const int src = sv.x;
                const float ea0 = ea[sv.y * 3 + 0];
                const float ea1v = ea[sv.y * 3 + 1];
                const float ea2v = ea[sv.y * 3 + 2];
                const float ep0 = fmaf(ea0, w00, fmaf(ea1v, w01, ea2v * w02));
                const float ep1 = fmaf(ea0, w10, fmaf(ea1v, w11, ea2v * w12));
                const unsigned short* kp = k16 + (size_t)src * DIM;
                const unsigned short* vp = v16 + (size_t)src * DIM;
                const float k0 = bf2f(kp[c0]) + ep0;
                const float k1 = bf2f(kp[c1]) + ep1;
                vv0[j] = bf2f(vp[c0]) + ep0;
                vv1[j] = bf2f(vp[c1]) + ep1;
                l[j] = fmaf(q0, k0, q1 * k1);
            } else {
                l[j] = -INFINITY;
                vv0[j] = 0.f;
                vv1[j] = 0.f;
            }
        }
        // 4 interleaved wave reduces (chain depth 6, width 4)
#pragma unroll
        for (int off = 32; off > 0; off >>= 1) {
#pragma unroll
            for (int j = 0; j < 4; ++j) l[j] += __shfl_xor(l[j], off, 64);
        }
        // merged online-softmax update (exp(-inf - mn) == 0 for pad slots)
        const float cm = fmaxf(fmaxf(l[0], l[1]), fmaxf(l[2], l[3]));
        const float mn = fmaxf(m, cm);
        const float sc = __expf(m - mn);        // 0 on first chunk (m = -inf)
        const float e0 = __expf(l[0] - mn), e1 = __expf(l[1] - mn);
        const float e2 = __expf(l[2] - mn), e3 = __expf(l[3] - mn);
        den = den * sc + ((e0 + e1) + (e2 + e3));
        a0 = a0 * sc + ((e0 * vv0[0] + e1 * vv0[1]) + (e2 * vv0[2] + e3 * vv0[3]));
        a1 = a1 * sc + ((e0 * vv1[0] + e1 * vv1[1]) + (e2 * vv1[2] + e3 * vv1[3]));
        m = mn;
    }
    const float inv = 1.f / (den + 1e-16f);
    out[(size_t)d * DIM + c0] += a0 * inv;
    out[(size_t)d * DIM + c1] += a1 * inv;
}

// h = relu(h) - relu(o1)   (in place)
__global__ __launch_bounds__(256) void combine_kernel(
    const float4* __restrict__ o1, float4* __restrict__ h)
{
    const int i = blockIdx.x * 256 + threadIdx.x;
    float4 a = o1[i];
    float4 b = h[i];
    float4 r;
    r.x = fmaxf(b.x, 0.f) - fmaxf(a.x, 0.f);
    r.y = fmaxf(b.y, 0.f) - fmaxf(a.y, 0.f);
    r.z = fmaxf(b.z, 0.f) - fmaxf(a.z, 0.f);
    r.w = fmaxf(b.w, 0.f) - fmaxf(a.w, 0.f);
    h[i] = r;
}

// Mean-pool prep: batchs sorted -> run accumulation, atomic flush per boundary.
__global__ __launch_bounds__(256) void pool_kernel(
    const float* __restrict__ h, const int* __restrict__ batchs,
    float* __restrict__ sums, float* __restrict__ cnt)
{
    const int sub = threadIdx.x >> 7;
    const int c = threadIdx.x & 127;
    int n0 = blockIdx.x * 32 + sub * 16;
    int nend = n0 + 16;
    if (nend > NNODES) nend = NNODES;
    float acc = 0.f, ccnt = 0.f;
    int curb = -1;
    for (int nd = n0; nd < nend; ++nd) {
        int b = batchs[nd];
        if (b != curb) {
            if (curb >= 0) {
                atomicAdd(&sums[curb * DIM + c], acc);
                if (c == 0) atomicAdd(&cnt[curb], ccnt);
            }
            acc = 0.f; ccnt = 0.f; curb = b;
        }
        acc += h[(size_t)nd * DIM + c];
        ccnt += 1.f;
    }
    if (curb >= 0) {
        atomicAdd(&sums[curb * DIM + c], acc);
        if (c == 0) atomicAdd(&cnt[curb], ccnt);
    }
}

// Whole MLP head per batch row.
__global__ __launch_bounds__(256) void head_kernel(
    const float* __restrict__ sums, const float* __restrict__ cnt,
    const float* __restrict__ l0w, const float* __restrict__ l0b,
    const float* __restrict__ l1w, const float* __restrict__ l1b,
    const float* __restrict__ l3w, const float* __restrict__ l3b,
    float* __restrict__ out)
{
    __shared__ float g[DIM];
    __shared__ float h0[DFC];
    __shared__ float h1[DFC];
    __shared__ float lg[2];
    const int b = blockIdx.x;
    const int tid = threadIdx.x;
    const float c = fmaxf(cnt[b], 1.0f);
    if (tid < DIM) g[tid] = sums[b * DIM + tid] / c;
    __syncthreads();
    for (int o = tid; o < DFC; o += 256) {
        float acc = l0b[o];
        for (int kk = 0; kk < DIM; ++kk) acc = fmaf(g[kk], l0w[o * DIM + kk], acc);
        h0[o] = fmaxf(acc, 0.f);
    }
    __syncthreads();
    for (int o = tid; o < DFC; o += 256) {
        float acc = l1b[o];
        for (int kk = 0; kk < DFC; ++kk) acc = fmaf(h0[kk], l1w[o * DFC + kk], acc);
        h1[o] = fmaxf(acc, 0.f);
    }
    __syncthreads();
    if (tid < 2) {
        float acc = l3b[tid];
        for (int kk = 0; kk < DFC; ++kk) acc = fmaf(h1[kk], l3w[tid * DFC + kk], acc);
        lg[tid] = acc;
    }
    __syncthreads();
    if (tid == 0) {
        float l0 = lg[0], l1v = lg[1];
        float mx = fmaxf(l0, l1v);
        float lse = mx + logf(expf(l0 - mx) + expf(l1v - mx));
        out[b * 2 + 0] = l0 - lse;
        out[b * 2 + 1] = l1v - lse;
    }
}

// ---------------------------------------------------------------------------
extern "C" void kernel_launch(void* const* d_in, const int* in_sizes, int n_in,
                              void* d_out, int out_size, void* d_ws, size_t ws_size,
                              hipStream_t stream)
{
    const float* x      = (const float*)d_in[0];
    const int*   ei1    = (const int*)d_in[1];
    const int*   ei2    = (const int*)d_in[2];
    const float* ea1    = (const float*)d_in[3];
    const float* ea2    = (const float*)d_in[4];
    const int*   batchs = (const int*)d_in[6];

    // workspace layout — ~217 MB total (k/v now bf16)
    float* ws_f = (float*)d_ws;
    const size_t ND = (size_t)NNODES * DIM;
    float* q    = ws_f;
    float* o1   = q + ND;
    float* h    = o1 + ND;                 // doubles as o2 and next-layer input
    unsigned short* k16 = (unsigned short*)(h + ND);   // ND bf16
    unsigned short* v16 = k16 + ND;                    // ND bf16
    float* sums = (float*)(v16 + ND);
    float* cnt  = sums + NB * DIM;
    short* whi  = (short*)(cnt + NB);      // 16 mats * 16384 bf16 (hi)
    short* wlo  = whi + 16 * 16384;
    int*   ip   = (int*)(wlo + 16 * 16384);
    int*  rowptr1 = ip;                    // N+1
    int*  rowptr2 = rowptr1 + (NNODES + 1);
    int*  pad     = rowptr2 + (NNODES + 1);            // keep int2 8B-aligned
    int2* sse1    = (int2*)(pad + ((((size_t)(pad)) & 4) ? 1 : 1));  // bump 1 int, then check
    // simpler: force alignment by rounding up to even int offset
    {
        size_t off = (size_t)(pad - ip);
        if (off & 1) pad += 1;
        sse1 = (int2*)pad;
    }
    int2* sse2    = sse1 + NEDGES;
    int*  deg     = (int*)(sse2 + NEDGES); // N temp
    int*  excl    = deg + NNODES;          // N temp (reused as fill)
    int*  bsum    = excl + NNODES;         // 512 temp

    // ---- Split all layer weights into bf16 hi/lo frag-major, once ----
    wsplit_kernel<<<128, 256, 0, stream>>>(
        (const float*)d_in[7], (const float*)d_in[9],
        (const float*)d_in[11], (const float*)d_in[14],
        (const float*)d_in[16], (const float*)d_in[18],
        (const float*)d_in[20], (const float*)d_in[23],
        whi, wlo);

    // ---- Build CSR (dst-sorted) for both edge sets ----
    for (int gi = 0; gi < 2; ++gi) {
        const int* ei = gi ? ei2 : ei1;
        int*  rowptr = gi ? rowptr2 : rowptr1;
        int2* sse    = gi ? sse2 : sse1;
        hipMemsetAsync(deg, 0, NNODES * sizeof(int), stream);
        hist_kernel<<<(NEDGES + 255) / 256, 256, 0, stream>>>(ei, deg);
        scan1_kernel<<<NB1, 256, 0, stream>>>(deg, excl, bsum);
        scan2_kernel<<<1, 512, 0, stream>>>(bsum);
        scan3_kernel<<<NB1, 256, 0, stream>>>(excl, bsum, rowptr);
        hipMemsetAsync(excl, 0, NNODES * sizeof(int), stream);   // reuse as fill
        scatter_edges_kernel<<<(NEDGES + 255) / 256, 256, 0, stream>>>(ei, rowptr, excl, sse);
    }

    // ---- Layers ----
    const float* xin = x;
    for (int li = 0; li < 4; ++li) {
        const float *bq_, *bk_, *bv_, *bs_, *we_;
        if (li == 0) {
            bq_ = (const float*)d_in[8];
            bk_ = (const float*)d_in[10];
            bv_ = (const float*)d_in[12];
            bs_ = (const float*)d_in[15];
            we_ = (const float*)d_in[13];
        } else {
            int i = li - 1;
            bq_ = (const float*)d_in[17] + (size_t)i * DIM;
            bk_ = (const float*)d_in[19] + (size_t)i * DIM;
            bv_ = (const float*)d_in[21] + (size_t)i * DIM;
            bs_ = (const float*)d_in[24] + (size_t)i * DIM;
            we_ = (const float*)d_in[22] + (size_t)i * DIM * 3;
        }

        qkvs_mfma_kernel<<<NNODES / 32, 256, 0, stream>>>(
            xin, whi + (size_t)li * 4 * 16384, wlo + (size_t)li * 4 * 16384,
            bq_, bk_, bv_, bs_, q, k16, v16, o1, h);

        attn_aggregate_kernel<<<(2 * NNODES + 3) / 4, 256, 0, stream>>>(
            rowptr1, sse1, ea1, rowptr2, sse2, ea2,
            we_, q, k16, v16, o1, h);

        combine_kernel<<<(int)(ND / 1024), 256, 0, stream>>>((const float4*)o1, (float4*)h);
        xin = h;
    }

    hipMemsetAsync(sums, 0, NB * DIM * sizeof(float), stream);
    hipMemsetAsync(cnt, 0, NB * sizeof(float), stream);
    pool_kernel<<<(NNODES + 31) / 32, 256, 0, stream>>>(h, batchs, sums, cnt);
    head_kernel<<<NB, 256, 0, stream>>>(sums, cnt,
        (const float*)d_in[25], (const float*)d_in[26],
        (const float*)d_in[27], (const float*)d_in[28],
        (const float*)d_in[29], (const float*)d_in[30],
        (float*)d_out);
}

// Round 11
// 1589.740 us; speedup vs baseline: 2.9491x; 1.1413x over previous
//
#include <hip/hip_runtime.h>

#define NNODES 100000
#define NEDGES 600000
#define DIM    128
#define NB     64
#define DFC    512
#define NB1    391   // ceil(NNODES/256) blocks for the scan

typedef __attribute__((ext_vector_type(8))) short short8v;
typedef __attribute__((ext_vector_type(4))) float float4v;

__device__ __forceinline__ float bf2f(unsigned short u) {
    return __uint_as_float((unsigned)u << 16);
}
__device__ __forceinline__ unsigned short f2bf(float f) {
    unsigned u = __float_as_uint(f);
    return (unsigned short)((u + 0x7FFF + ((u >> 16) & 1)) >> 16);   // RNE
}

// ---------------------------------------------------------------------------
// Split all 16 layer weight matrices into bf16 hi/lo, stored MFMA-frag-major.
__global__ __launch_bounds__(256) void wsplit_kernel(
    const float* __restrict__ c1q, const float* __restrict__ c1k,
    const float* __restrict__ c1v, const float* __restrict__ c1s,
    const float* __restrict__ csq, const float* __restrict__ csk,
    const float* __restrict__ csv, const float* __restrict__ css,
    short* __restrict__ whi, short* __restrict__ wlo)
{
    int t = blockIdx.x * 256 + threadIdx.x;     // 0..32767
    int mat = t >> 11;                          // 0..15
    int tt = t & 2047;
    int lane = tt & 63, nt = (tt >> 6) & 7, ks = tt >> 9;
    int li = mat >> 2, mm = mat & 3;
    const float* W;
    if (li == 0) W = (mm == 0) ? c1q : (mm == 1) ? c1k : (mm == 2) ? c1v : c1s;
    else {
        const float* base = (mm == 0) ? csq : (mm == 1) ? csk : (mm == 2) ? csv : css;
        W = base + (size_t)(li - 1) * 16384;
    }
    int n = nt * 16 + (lane & 15);
    int k0 = ks * 32 + (lane >> 4) * 8;
    size_t ob = (size_t)mat * 16384 + (size_t)((ks * 8 + nt) * 64 + lane) * 8;
#pragma unroll
    for (int j = 0; j < 8; ++j) {
        float w = W[n * 128 + k0 + j];
        unsigned ub = __float_as_uint(w);
        float lo = w - __uint_as_float(ub & 0xFFFF0000u);
        whi[ob + j] = (short)(ub >> 16);
        wlo[ob + j] = (short)(__float_as_uint(lo) >> 16);
    }
}

// ---------------------------------------------------------------------------
// Split-bf16 MFMA fused q/k/v/skip GEMM. q and skip stored f32; k and v
// stored bf16 (RNE). x is read-only here (attn writes h later) -> no barrier.
__global__ __launch_bounds__(256) void qkvs_mfma_kernel(
    const float* __restrict__ x,
    const short* __restrict__ whi, const short* __restrict__ wlo,
    const float* __restrict__ bq, const float* __restrict__ bk,
    const float* __restrict__ bv, const float* __restrict__ bs,
    float* __restrict__ q, unsigned short* __restrict__ k16,
    unsigned short* __restrict__ v16, float* __restrict__ s)
{
    const int lane = threadIdx.x & 63;
    const int m = threadIdx.x >> 6;
    const int r0 = blockIdx.x * 32;
    const int lrow = lane & 15;
    const int lgrp = lane >> 4;

    float4v acc[2][8] = {};
    const short* Whi = whi + (size_t)m * 16384;
    const short* Wlo = wlo + (size_t)m * 16384;

    for (int ks = 0; ks < 4; ++ks) {
        short8v ahi[2], alo[2];
#pragma unroll
        for (int mt = 0; mt < 2; ++mt) {
            const float* xp = x + (size_t)(r0 + mt * 16 + lrow) * DIM + ks * 32 + lgrp * 8;
            float4 xa = *(const float4*)xp;
            float4 xb = *(const float4*)(xp + 4);
            float xs[8] = {xa.x, xa.y, xa.z, xa.w, xb.x, xb.y, xb.z, xb.w};
#pragma unroll
            for (int j = 0; j < 8; ++j) {
                unsigned ub = __float_as_uint(xs[j]);
                float lo = xs[j] - __uint_as_float(ub & 0xFFFF0000u);
                ahi[mt][j] = (short)(ub >> 16);
                alo[mt][j] = (short)(__float_as_uint(lo) >> 16);
            }
        }
        const short* bh = Whi + (size_t)((ks * 8) * 64 + lane) * 8;
        const short* bl = Wlo + (size_t)((ks * 8) * 64 + lane) * 8;
#pragma unroll
        for (int nt = 0; nt < 8; ++nt) {
            short8v bhi = *(const short8v*)(bh + (size_t)nt * 512);
            short8v blo = *(const short8v*)(bl + (size_t)nt * 512);
#pragma unroll
            for (int mt = 0; mt < 2; ++mt) {
                acc[mt][nt] = __builtin_amdgcn_mfma_f32_16x16x32_bf16(ahi[mt], bhi, acc[mt][nt], 0, 0, 0);
                acc[mt][nt] = __builtin_amdgcn_mfma_f32_16x16x32_bf16(ahi[mt], blo, acc[mt][nt], 0, 0, 0);
                acc[mt][nt] = __builtin_amdgcn_mfma_f32_16x16x32_bf16(alo[mt], bhi, acc[mt][nt], 0, 0, 0);
            }
        }
    }

    const float* bias = (m == 0) ? bq : (m == 1) ? bk : (m == 2) ? bv : bs;
#pragma unroll
    for (int nt = 0; nt < 8; ++nt) {
        float bvv = bias[nt * 16 + lrow];
#pragma unroll
        for (int mt = 0; mt < 2; ++mt) {
#pragma unroll
            for (int i = 0; i < 4; ++i) {
                int row = r0 + mt * 16 + lgrp * 4 + i;
                float val = acc[mt][nt][i] + bvv;
                size_t off = (size_t)row * DIM + nt * 16 + lrow;
                if (m == 0) q[off] = val;
                else if (m == 1) k16[off] = f2bf(val);
                else if (m == 2) v16[off] = f2bf(val);
                else s[off] = val;
            }
        }
    }
}

// ---------------------------------------------------------------------------
// CSR build: histogram -> exclusive scan -> scatter (src + ea permuted).
__global__ __launch_bounds__(256) void hist_kernel(const int* __restrict__ ei,
                                                   int* __restrict__ deg) {
    int e = blockIdx.x * 256 + threadIdx.x;
    if (e < NEDGES) atomicAdd(&deg[ei[NEDGES + e]], 1);
}

__global__ __launch_bounds__(256) void scan1_kernel(const int* __restrict__ deg,
                                                    int* __restrict__ excl,
                                                    int* __restrict__ bsum) {
    __shared__ int s[256];
    const int tid = threadIdx.x;
    const int i = blockIdx.x * 256 + tid;
    const int v = (i < NNODES) ? deg[i] : 0;
    s[tid] = v;
    __syncthreads();
    for (int off = 1; off < 256; off <<= 1) {
        int t = (tid >= off) ? s[tid - off] : 0;
        __syncthreads();
        s[tid] += t;
        __syncthreads();
    }
    if (i < NNODES) excl[i] = s[tid] - v;
    if (tid == 255) bsum[blockIdx.x] = s[255];
}

__global__ __launch_bounds__(512) void scan2_kernel(int* __restrict__ bsum) {
    __shared__ int s[512];
    const int tid = threadIdx.x;
    const int v = (tid < NB1) ? bsum[tid] : 0;
    s[tid] = v;
    __syncthreads();
    for (int off = 1; off < 512; off <<= 1) {
        int t = (tid >= off) ? s[tid - off] : 0;
        __syncthreads();
        s[tid] += t;
        __syncthreads();
    }
    if (tid < NB1) bsum[tid] = s[tid] - v;   // exclusive
}

__global__ __launch_bounds__(256) void scan3_kernel(const int* __restrict__ excl,
                                                    const int* __restrict__ bsum,
                                                    int* __restrict__ rowptr) {
    const int i = blockIdx.x * 256 + threadIdx.x;
    if (i < NNODES) rowptr[i] = excl[i] + bsum[blockIdx.x];
    if (i == 0) rowptr[NNODES] = NEDGES;
}

__global__ __launch_bounds__(256) void scatter_edges_kernel(
    const int* __restrict__ ei, const float* __restrict__ ea,
    const int* __restrict__ rowptr, int* __restrict__ fill,
    int* __restrict__ ssrc, float* __restrict__ eas) {
    int e = blockIdx.x * 256 + threadIdx.x;
    if (e >= NEDGES) return;
    int dst = ei[NEDGES + e];
    int pos = rowptr[dst] + atomicAdd(&fill[dst], 1);
    ssrc[pos] = ei[e];
    eas[pos * 3 + 0] = ea[e * 3 + 0];
    eas[pos * 3 + 1] = ea[e * 3 + 1];
    eas[pos * 3 + 2] = ea[e * 3 + 2];
}

// ---------------------------------------------------------------------------
// Fused edge phase + combine. One wave per dst node, BOTH graphs serially:
// chunk-4 edges, bf16 k/v gathers, sequential eas reads, merged online
// softmax; epilogue writes h = relu(s + r2) - relu(s + r1). No atomics,
// no RMW, combine kernel eliminated.
__device__ __forceinline__ void edge_pass(
    const int* __restrict__ rowptr, const int* __restrict__ ssrc,
    const float* __restrict__ eas,
    const unsigned short* __restrict__ k16, const unsigned short* __restrict__ v16,
    int d, int c0, int c1,
    float w00, float w01, float w02, float w10, float w11, float w12,
    float q0, float q1, float& r0, float& r1)
{
    const int p0 = rowptr[d], p1 = rowptr[d + 1];
    float m = -INFINITY, den = 0.f, a0 = 0.f, a1 = 0.f;
    for (int p = p0; p < p1; p += 4) {
        const int nn = p1 - p;                   // wave-uniform
        float l[4], vv0[4], vv1[4];
#pragma unroll
        for (int j = 0; j < 4; ++j) {
            if (j < nn) {
                const int src = ssrc[p + j];
                const float ea0 = eas[(p + j) * 3 + 0];
                const float ea1v = eas[(p + j) * 3 + 1];
                const float ea2v = eas[(p + j) * 3 + 2];
                const float ep0 = fmaf(ea0, w00, fmaf(ea1v, w01, ea2v * w02));
                const float ep1 = fmaf(ea0, w10, fmaf(ea1v, w11, ea2v * w12));
                const unsigned short* kp = k16 + (size_t)src * DIM;
                const unsigned short* vp = v16 + (size_t)src * DIM;
                const float k0 = bf2f(kp[c0]) + ep0;
                const float k1 = bf2f(kp[c1]) + ep1;
                vv0[j] = bf2f(vp[c0]) + ep0;
                vv1[j] = bf2f(vp[c1]) + ep1;
                l[j] = fmaf(q0, k0, q1 * k1);
            } else {
                l[j] = -INFINITY;
                vv0[j] = 0.f;
                vv1[j] = 0.f;
            }
        }
#pragma unroll
        for (int off = 32; off > 0; off >>= 1) {
#pragma unroll
            for (int j = 0; j < 4; ++j) l[j] += __shfl_xor(l[j], off, 64);
        }
        const float cm = fmaxf(fmaxf(l[0], l[1]), fmaxf(l[2], l[3]));
        const float mn = fmaxf(m, cm);
        const float sc = __expf(m - mn);        // 0 on first chunk (m = -inf)
        const float e0 = __expf(l[0] - mn), e1 = __expf(l[1] - mn);
        const float e2 = __expf(l[2] - mn), e3 = __expf(l[3] - mn);
        den = den * sc + ((e0 + e1) + (e2 + e3));
        a0 = a0 * sc + ((e0 * vv0[0] + e1 * vv0[1]) + (e2 * vv0[2] + e3 * vv0[3]));
        a1 = a1 * sc + ((e0 * vv1[0] + e1 * vv1[1]) + (e2 * vv1[2] + e3 * vv1[3]));
        m = mn;
    }
    const float inv = 1.f / (den + 1e-16f);     // den==0 -> a==0 -> r=0
    r0 = a0 * inv;
    r1 = a1 * inv;
}

__global__ __launch_bounds__(256) void attn_aggregate_kernel(
    const int* __restrict__ rowptr1, const int* __restrict__ ssrc1,
    const float* __restrict__ eas1,
    const int* __restrict__ rowptr2, const int* __restrict__ ssrc2,
    const float* __restrict__ eas2,
    const float* __restrict__ we,
    const float* __restrict__ q, const unsigned short* __restrict__ k16,
    const unsigned short* __restrict__ v16,
    const float* __restrict__ s, float* __restrict__ h)
{
    const int wave = threadIdx.x >> 6;
    const int lane = threadIdx.x & 63;
    const int d = blockIdx.x * 4 + wave;          // grid = NNODES/4 exactly
    const int c0 = lane, c1 = lane + 64;
    const float w00 = we[c0 * 3 + 0], w01 = we[c0 * 3 + 1], w02 = we[c0 * 3 + 2];
    const float w10 = we[c1 * 3 + 0], w11 = we[c1 * 3 + 1], w12 = we[c1 * 3 + 2];
    const float scale = 0.08838834764831845f;   // 1/sqrt(128)
    const float q0 = q[(size_t)d * DIM + c0] * scale;
    const float q1 = q[(size_t)d * DIM + c1] * scale;
    const float s0 = s[(size_t)d * DIM + c0];
    const float s1 = s[(size_t)d * DIM + c1];

    float r1_0, r1_1, r2_0, r2_1;
    edge_pass(rowptr1, ssrc1, eas1, k16, v16, d, c0, c1,
              w00, w01, w02, w10, w11, w12, q0, q1, r1_0, r1_1);
    edge_pass(rowptr2, ssrc2, eas2, k16, v16, d, c0, c1,
              w00, w01, w02, w10, w11, w12, q0, q1, r2_0, r2_1);

    h[(size_t)d * DIM + c0] = fmaxf(s0 + r2_0, 0.f) - fmaxf(s0 + r1_0, 0.f);
    h[(size_t)d * DIM + c1] = fmaxf(s1 + r2_1, 0.f) - fmaxf(s1 + r1_1, 0.f);
}

// Mean-pool prep: batchs sorted -> run accumulation, atomic flush per boundary.
__global__ __launch_bounds__(256) void pool_kernel(
    const float* __restrict__ h, const int* __restrict__ batchs,
    float* __restrict__ sums, float* __restrict__ cnt)
{
    const int sub = threadIdx.x >> 7;
    const int c = threadIdx.x & 127;
    int n0 = blockIdx.x * 32 + sub * 16;
    int nend = n0 + 16;
    if (nend > NNODES) nend = NNODES;
    float acc = 0.f, ccnt = 0.f;
    int curb = -1;
    for (int nd = n0; nd < nend; ++nd) {
        int b = batchs[nd];
        if (b != curb) {
            if (curb >= 0) {
                atomicAdd(&sums[curb * DIM + c], acc);
                if (c == 0) atomicAdd(&cnt[curb], ccnt);
            }
            acc = 0.f; ccnt = 0.f; curb = b;
        }
        acc += h[(size_t)nd * DIM + c];
        ccnt += 1.f;
    }
    if (curb >= 0) {
        atomicAdd(&sums[curb * DIM + c], acc);
        if (c == 0) atomicAdd(&cnt[curb], ccnt);
    }
}

// Whole MLP head per batch row.
__global__ __launch_bounds__(256) void head_kernel(
    const float* __restrict__ sums, const float* __restrict__ cnt,
    const float* __restrict__ l0w, const float* __restrict__ l0b,
    const float* __restrict__ l1w, const float* __restrict__ l1b,
    const float* __restrict__ l3w, const float* __restrict__ l3b,
    float* __restrict__ out)
{
    __shared__ float g[DIM];
    __shared__ float h0[DFC];
    __shared__ float h1[DFC];
    __shared__ float lg[2];
    const int b = blockIdx.x;
    const int tid = threadIdx.x;
    const float c = fmaxf(cnt[b], 1.0f);
    if (tid < DIM) g[tid] = sums[b * DIM + tid] / c;
    __syncthreads();
    for (int o = tid; o < DFC; o += 256) {
        float acc = l0b[o];
        for (int kk = 0; kk < DIM; ++kk) acc = fmaf(g[kk], l0w[o * DIM + kk], acc);
        h0[o] = fmaxf(acc, 0.f);
    }
    __syncthreads();
    for (int o = tid; o < DFC; o += 256) {
        float acc = l1b[o];
        for (int kk = 0; kk < DFC; ++kk) acc = fmaf(h0[kk], l1w[o * DFC + kk], acc);
        h1[o] = fmaxf(acc, 0.f);
    }
    __syncthreads();
    if (tid < 2) {
        float acc = l3b[tid];
        for (int kk = 0; kk < DFC; ++kk) acc = fmaf(h1[kk], l3w[tid * DFC + kk], acc);
        lg[tid] = acc;
    }
    __syncthreads();
    if (tid == 0) {
        float l0 = lg[0], l1v = lg[1];
        float mx = fmaxf(l0, l1v);
        float lse = mx + logf(expf(l0 - mx) + expf(l1v - mx));
        out[b * 2 + 0] = l0 - lse;
        out[b * 2 + 1] = l1v - lse;
    }
}

// ---------------------------------------------------------------------------
extern "C" void kernel_launch(void* const* d_in, const int* in_sizes, int n_in,
                              void* d_out, int out_size, void* d_ws, size_t ws_size,
                              hipStream_t stream)
{
    const float* x      = (const float*)d_in[0];
    const int*   ei1    = (const int*)d_in[1];
    const int*   ei2    = (const int*)d_in[2];
    const float* ea1    = (const float*)d_in[3];
    const float* ea2    = (const float*)d_in[4];
    const int*   batchs = (const int*)d_in[6];

    // workspace layout — ~226 MB total, <= 256 MiB
    float* ws_f = (float*)d_ws;
    const size_t ND = (size_t)NNODES * DIM;
    float* q    = ws_f;
    float* sbuf = q + ND;                  // skip
    float* h    = sbuf + ND;               // layer output / next input
    unsigned short* k16 = (unsigned short*)(h + ND);   // ND bf16
    unsigned short* v16 = k16 + ND;                    // ND bf16
    float* sums = (float*)(v16 + ND);
    float* cnt  = sums + NB * DIM;
    short* whi  = (short*)(cnt + NB);      // 16 mats * 16384 bf16 (hi)
    short* wlo  = whi + 16 * 16384;
    float* eas1 = (float*)(wlo + 16 * 16384);   // E*3 CSR-ordered edge_attr
    float* eas2 = eas1 + (size_t)NEDGES * 3;
    int*   ip   = (int*)(eas2 + (size_t)NEDGES * 3);
    int* rowptr1 = ip;                     // N+1
    int* rowptr2 = rowptr1 + (NNODES + 1);
    int* ssrc1   = rowptr2 + (NNODES + 1); // E
    int* ssrc2   = ssrc1 + NEDGES;
    int* deg     = ssrc2 + NEDGES;         // N temp
    int* excl    = deg + NNODES;           // N temp (reused as fill)
    int* bsum    = excl + NNODES;          // 512 temp

    // ---- Split all layer weights into bf16 hi/lo frag-major, once ----
    wsplit_kernel<<<128, 256, 0, stream>>>(
        (const float*)d_in[7], (const float*)d_in[9],
        (const float*)d_in[11], (const float*)d_in[14],
        (const float*)d_in[16], (const float*)d_in[18],
        (const float*)d_in[20], (const float*)d_in[23],
        whi, wlo);

    // ---- Build CSR (dst-sorted, ea permuted) for both edge sets ----
    for (int gi = 0; gi < 2; ++gi) {
        const int*   ei = gi ? ei2 : ei1;
        const float* ea = gi ? ea2 : ea1;
        int*   rowptr = gi ? rowptr2 : rowptr1;
        int*   ssrc   = gi ? ssrc2 : ssrc1;
        float* eas    = gi ? eas2 : eas1;
        hipMemsetAsync(deg, 0, NNODES * sizeof(int), stream);
        hist_kernel<<<(NEDGES + 255) / 256, 256, 0, stream>>>(ei, deg);
        scan1_kernel<<<NB1, 256, 0, stream>>>(deg, excl, bsum);
        scan2_kernel<<<1, 512, 0, stream>>>(bsum);
        scan3_kernel<<<NB1, 256, 0, stream>>>(excl, bsum, rowptr);
        hipMemsetAsync(excl, 0, NNODES * sizeof(int), stream);   // reuse as fill
        scatter_edges_kernel<<<(NEDGES + 255) / 256, 256, 0, stream>>>(ei, ea, rowptr, excl, ssrc, eas);
    }

    // ---- Layers ----
    const float* xin = x;
    for (int li = 0; li < 4; ++li) {
        const float *bq_, *bk_, *bv_, *bs_, *we_;
        if (li == 0) {
            bq_ = (const float*)d_in[8];
            bk_ = (const float*)d_in[10];
            bv_ = (const float*)d_in[12];
            bs_ = (const float*)d_in[15];
            we_ = (const float*)d_in[13];
        } else {
            int i = li - 1;
            bq_ = (const float*)d_in[17] + (size_t)i * DIM;
            bk_ = (const float*)d_in[19] + (size_t)i * DIM;
            bv_ = (const float*)d_in[21] + (size_t)i * DIM;
            bs_ = (const float*)d_in[24] + (size_t)i * DIM;
            we_ = (const float*)d_in[22] + (size_t)i * DIM * 3;
        }

        qkvs_mfma_kernel<<<NNODES / 32, 256, 0, stream>>>(
            xin, whi + (size_t)li * 4 * 16384, wlo + (size_t)li * 4 * 16384,
            bq_, bk_, bv_, bs_, q, k16, v16, sbuf);

        attn_aggregate_kernel<<<NNODES / 4, 256, 0, stream>>>(
            rowptr1, ssrc1, eas1, rowptr2, ssrc2, eas2,
            we_, q, k16, v16, sbuf, h);

        xin = h;
    }

    hipMemsetAsync(sums, 0, NB * DIM * sizeof(float), stream);
    hipMemsetAsync(cnt, 0, NB * sizeof(float), stream);
    pool_kernel<<<(NNODES + 31) / 32, 256, 0, stream>>>(h, batchs, sums, cnt);
    head_kernel<<<NB, 256, 0, stream>>>(sums, cnt,
        (const float*)d_in[25], (const float*)d_in[26],
        (const float*)d_in[27], (const float*)d_in[28],
        (const float*)d_in[29], (const float*)d_in[30],
        (float*)d_out);
}